// Round 3
// baseline (2316.606 us; speedup 1.0000x reference)
//
#include <hip/hip_runtime.h>
#include <hip/hip_bf16.h>

#define NUSERS 100000
#define NITEMS 50000
#define NEDGE  1000000   // both social and like edge lists are 1M
#define NBATCH 16384

// ---- workspace layout (floats), total 9,895,728 floats = 39,582,912 bytes ----
#define OFF_RU1C  250000                          // after sdeg/udeg/ideg
#define OFF_RU2C  (OFF_RU1C + NBATCH * 64)
#define OFF_SOC2C (OFF_RU2C + NBATCH * 64)
#define OFF_SLOT  (OFF_SOC2C + NBATCH * 64)       // 3,395,728
#define OFF_BIG   (OFF_SLOT + NUSERS)             // 3,495,728
#define WS_FLOATS (OFF_BIG + NUSERS * 64)         // 9,895,728

// ---- degrees (3 histograms) + slot map build ----
__global__ void k_deg_slot(const int* __restrict__ lu, const int* __restrict__ li,
                           const int* __restrict__ sd, float* __restrict__ udeg,
                           float* __restrict__ ideg, float* __restrict__ sdeg,
                           const int* __restrict__ users, int* __restrict__ slot) {
    int e = blockIdx.x * blockDim.x + threadIdx.x;
    if (e < NEDGE) {
        unsafeAtomicAdd(&udeg[lu[e]], 1.0f);
        unsafeAtomicAdd(&ideg[li[e]], 1.0f);
        unsafeAtomicAdd(&sdeg[sd[e]], 1.0f);
    }
    if (e < NBATCH) slot[users[e]] = e;  // duplicate users race: any winner is fine
}

// ---- full scatter: acc[di[e]] += src[si[e]]  (16 thr/edge, 4 dims each) ----
__global__ void k_scat_full(const int* __restrict__ si, const int* __restrict__ di,
                            const float* __restrict__ src, float* __restrict__ acc) {
    int t = blockIdx.x * blockDim.x + threadIdx.x;
    int e = t >> 4;
    if (e >= NEDGE) return;
    int q = (t & 15) << 2;
    float4 v = *(const float4*)(src + si[e] * 64 + q);
    float* o = acc + di[e] * 64 + q;
    unsafeAtomicAdd(o + 0, v.x);
    unsafeAtomicAdd(o + 1, v.y);
    unsafeAtomicAdd(o + 2, v.z);
    unsafeAtomicAdd(o + 3, v.w);
}

// ---- compact scatter: accc[slot[di[e]]] += src[si[e]] if di in batch ----
__global__ void k_scatc(const int* __restrict__ si, const int* __restrict__ di,
                        const int* __restrict__ slot, const float* __restrict__ src,
                        float* __restrict__ accc) {
    int t = blockIdx.x * blockDim.x + threadIdx.x;
    int e = t >> 4;
    if (e >= NEDGE) return;
    int sl = slot[di[e]];
    if (sl < 0) return;
    int q = (t & 15) << 2;
    float4 v = *(const float4*)(src + si[e] * 64 + q);
    float* o = accc + sl * 64 + q;
    unsafeAtomicAdd(o + 0, v.x);
    unsafeAtomicAdd(o + 1, v.y);
    unsafeAtomicAdd(o + 2, v.z);
    unsafeAtomicAdd(o + 3, v.w);
}

// ---- item combine (in place over BIG): ri1 = i_sw*ie + acc/max(ideg,1) ----
__global__ void k_node_i(const float* __restrict__ iemb, const float* __restrict__ ideg,
                         float* __restrict__ ri1) {
    int t = blockIdx.x * blockDim.x + threadIdx.x;
    if (t >= NITEMS * 16) return;
    int i = t >> 4, q = (t & 15) << 2;
    float dg = ideg[i];
    float inv = 1.0f / fmaxf(dg, 1.0f);
    float sw = 1.0f - dg / (dg + 1e-8f);     // 1 if deg==0, ~0 otherwise (f32 exact-ish)
    int off = i * 64 + q;
    float4 r = *(float4*)(ri1 + off);
    float4 ev = *(const float4*)(iemb + off);
    r.x = sw * ev.x + r.x * inv;
    r.y = sw * ev.y + r.y * inv;
    r.z = sw * ev.z + r.z * inv;
    r.w = sw * ev.w + r.w * inv;
    *(float4*)(ri1 + off) = r;
}

// ---- social combine (in place over BIG): soc1 = acc/max(sdeg,1) ----
__global__ void k_node_s(const float* __restrict__ sdeg, float* __restrict__ soc1) {
    int t = blockIdx.x * blockDim.x + threadIdx.x;
    if (t >= NUSERS * 16) return;
    int u = t >> 4, q = (t & 15) << 2;
    float inv = 1.0f / fmaxf(sdeg[u], 1.0f);
    int off = u * 64 + q;
    float4 s = *(float4*)(soc1 + off);
    s.x *= inv; s.y *= inv; s.z *= inv; s.w *= inv;
    *(float4*)(soc1 + off) = s;
}

// ---- epilogue: one 64-lane wave per batch element ----
__global__ void k_out(const int* __restrict__ users, const int* __restrict__ items,
                      const float* __restrict__ uemb, const float* __restrict__ iemb,
                      const float* __restrict__ soc1, const float* __restrict__ ru1c,
                      const float* __restrict__ ru2c, const float* __restrict__ soc2c,
                      const int* __restrict__ slot, const float* __restrict__ sdeg,
                      const float* __restrict__ udeg, float* __restrict__ out) {
    int b = blockIdx.x;
    int d = threadIdx.x;  // 0..63
    int u = users[b], it = items[b], sl = slot[u];
    float sd = fmaxf(sdeg[u], 1.0f);
    float ud = udeg[u];
    float um = fmaxf(ud, 1.0f);
    float usw = 1.0f - ud / (ud + 1e-8f);
    float ue = uemb[u * 64 + d];
    float s1 = soc1[u * 64 + d];                  // already a mean
    float r1 = usw * ue + ru1c[sl * 64 + d] / um;
    float s2 = soc2c[sl * 64 + d] / sd;
    float r2 = usw * r1 + ru2c[sl * 64 + d] / um;
    float fu = ue + 0.5f * (s1 + r1) + 0.5f * (s2 + r2);
    float iv = iemb[it * 64 + d];
    out[NBATCH + b * 64 + d]               = fu;
    out[NBATCH + NBATCH * 64 + b * 64 + d] = iv;
    float p = fu * iv;
    #pragma unroll
    for (int o = 32; o > 0; o >>= 1) p += __shfl_down(p, o);
    if (d == 0) out[b] = 1.0f / (1.0f + __expf(-p));
}

extern "C" void kernel_launch(void* const* d_in, const int* in_sizes, int n_in,
                              void* d_out, int out_size, void* d_ws, size_t ws_size,
                              hipStream_t stream) {
    const float* uemb  = (const float*)d_in[0];   // [100000,64] f32
    const float* iemb  = (const float*)d_in[1];   // [50000,64]  f32
    const int*   users = (const int*)d_in[2];
    const int*   items = (const int*)d_in[3];
    const int*   ssrc  = (const int*)d_in[4];
    const int*   sdst  = (const int*)d_in[5];
    const int*   lu    = (const int*)d_in[6];
    const int*   li    = (const int*)d_in[7];
    float* out = (float*)d_out;

    if (ws_size < (size_t)WS_FLOATS * 4) return;  // would show absmax==0.5 diagnostic

    float* ws    = (float*)d_ws;
    float* sdeg  = ws;
    float* udeg  = ws + NUSERS;
    float* ideg  = ws + 2 * NUSERS;
    float* ru1c  = ws + OFF_RU1C;
    float* ru2c  = ws + OFF_RU2C;
    float* soc2c = ws + OFF_SOC2C;
    int*   slot  = (int*)(ws + OFF_SLOT);
    float* big   = ws + OFF_BIG;   // ri1 acc, then soc1 acc

    hipMemsetAsync(ws, 0, (size_t)OFF_SLOT * 4, stream);          // degrees + compacts
    hipMemsetAsync(slot, 0xFF, (size_t)NUSERS * 4, stream);       // slot = -1

    const int B = 256;
    const int gE = (NEDGE + B - 1) / B;        // 1 thread/edge
    const int gS = (NEDGE * 16) / B;           // 16 threads/edge

    k_deg_slot<<<gE, B, 0, stream>>>(lu, li, sdst, udeg, ideg, sdeg, users, slot);

    // ---- rating branch ----
    k_scatc<<<gS, B, 0, stream>>>(li, lu, slot, iemb, ru1c);       // rat_u1 sums @ batch
    hipMemsetAsync(big, 0, (size_t)NITEMS * 64 * 4, stream);       // 12.8 MB
    k_scat_full<<<gS, B, 0, stream>>>(lu, li, uemb, big);          // ri1 acc (full)
    k_node_i<<<(NITEMS * 16 + B - 1) / B, B, 0, stream>>>(iemb, ideg, big);
    k_scatc<<<gS, B, 0, stream>>>(li, lu, slot, big, ru2c);        // rat_u2 sums @ batch

    // ---- social branch (reuse BIG) ----
    hipMemsetAsync(big, 0, (size_t)NUSERS * 64 * 4, stream);       // 25.6 MB
    k_scat_full<<<gS, B, 0, stream>>>(ssrc, sdst, uemb, big);      // soc1 acc (full)
    k_node_s<<<(NUSERS * 16 + B - 1) / B, B, 0, stream>>>(sdeg, big);
    k_scatc<<<gS, B, 0, stream>>>(ssrc, sdst, slot, big, soc2c);   // soc2 sums @ batch

    // ---- epilogue ----
    k_out<<<NBATCH, 64, 0, stream>>>(users, items, uemb, iemb, big, ru1c, ru2c,
                                     soc2c, slot, sdeg, udeg, out);
}

// Round 5
// 676.541 us; speedup vs baseline: 3.4242x; 3.4242x over previous
//
#include <hip/hip_runtime.h>
#include <hip/hip_bf16.h>

#define NUSERS 100000
#define NITEMS 50000
#define NEDGE  1000000
#define NBATCH 16384

// ---- workspace layout, units of 4 bytes (total 8,245,744 units = 33.0 MB) ----
// Overlay liveness: soc1 (3.2M units) overlays csrli+csrlu+ri1 (3.6M units),
// ALL dead before k_gather_soc runs. csrsd is in its own region (stays live).
#define OFF_CUR    0                         // 16 ints (3 scan cursors + pad)
#define OFF_IDEG   16                        // NITEMS int
#define OFF_UDEG   (OFF_IDEG + NITEMS)       // NUSERS int (out-degree on like_u)
#define OFF_SDEG   (OFF_UDEG + NUSERS)       // NUSERS int (in-degree on social_dst)
#define OFF_HEND   (OFF_SDEG + NUSERS)       // end of memset-0 region
#define OFF_IPTR   OFF_HEND                  // NITEMS
#define OFF_UPTR   (OFF_IPTR + NITEMS)       // NUSERS
#define OFF_SPTR   (OFF_UPTR + NUSERS)       // NUSERS
#define OFF_RU1C   (OFF_SPTR + NUSERS)       // NBATCH*64 f32
#define OFF_RU2C   (OFF_RU1C + NBATCH * 64)  // NBATCH*64 f32
#define OFF_SOC2C  (OFF_RU2C + NBATCH * 64)  // NBATCH*64 f32
#define OFF_CSRSD  (OFF_SOC2C + NBATCH * 64) // NEDGE int: social srcs grouped by dst  (LIVE through social branch)
#define OFF_CSRLI  (OFF_CSRSD + NEDGE)       // NEDGE int: users grouped by item       (dead after gather_item)
#define OFF_CSRLU  (OFF_CSRLI + NEDGE)       // NEDGE int: items grouped by user       (dead after batch_rat)
#define OFF_RI1    (OFF_CSRLU + NEDGE)       // NITEMS*64 bf16 = NITEMS*32 units       (dead after batch_rat)
#define OFF_SOC1   OFF_CSRLI                 // NUSERS*64 bf16 = 3.2M units overlay
#define WS_FLOATS  (OFF_RI1 + NITEMS * 32)   // 8,245,744

typedef __hip_bfloat16 bf16;

// ---- 3 int histograms in one pass ----
__global__ void k_hist(const int* __restrict__ lu, const int* __restrict__ li,
                       const int* __restrict__ sd, int* __restrict__ udeg,
                       int* __restrict__ ideg, int* __restrict__ sdeg) {
    int e = blockIdx.x * blockDim.x + threadIdx.x;
    if (e >= NEDGE) return;
    atomicAdd(&udeg[lu[e]], 1);
    atomicAdd(&ideg[li[e]], 1);
    atomicAdd(&sdeg[sd[e]], 1);
}

// ---- segment-start assignment: block-local exclusive scan + global cursor.
//      Segment ORDER across blocks is arbitrary; only contiguity matters. ----
__global__ void k_scan(const int* __restrict__ deg, int* __restrict__ ptr, int n,
                       int* __restrict__ cursor) {
    __shared__ int s[256];
    __shared__ int sbase;
    int g = blockIdx.x * 256 + threadIdx.x;
    int v = (g < n) ? deg[g] : 0;
    s[threadIdx.x] = v;
    __syncthreads();
    for (int o = 1; o < 256; o <<= 1) {          // Hillis-Steele inclusive scan
        int t = (threadIdx.x >= (unsigned)o) ? s[threadIdx.x - o] : 0;
        __syncthreads();
        s[threadIdx.x] += t;
        __syncthreads();
    }
    if (threadIdx.x == 255) sbase = atomicAdd(cursor, s[255]);
    __syncthreads();
    if (g < n) ptr[g] = sbase + s[threadIdx.x] - v;   // exclusive start
}

// ---- permute edges into 3 CSRs; ptr[] advances start->end ----
__global__ void k_permute(const int* __restrict__ lu, const int* __restrict__ li,
                          const int* __restrict__ ssrc, const int* __restrict__ sdst,
                          int* __restrict__ iptr, int* __restrict__ uptr,
                          int* __restrict__ sptr, int* __restrict__ csr_li,
                          int* __restrict__ csr_lu, int* __restrict__ csr_sd) {
    int e = blockIdx.x * blockDim.x + threadIdx.x;
    if (e >= NEDGE) return;
    int a = lu[e], b = li[e];
    csr_li[atomicAdd(&iptr[b], 1)] = a;   // item  <- liking users
    csr_lu[atomicAdd(&uptr[a], 1)] = b;   // user  <- liked items
    int s = ssrc[e], d = sdst[e];
    csr_sd[atomicAdd(&sptr[d], 1)] = s;   // user  <- social sources
}

// ---- ri1 = i_sw*iemb + mean(uemb[liking users]); one wave per item ----
__global__ void k_gather_item(const float* __restrict__ iemb,
                              const float* __restrict__ uemb,
                              const int* __restrict__ csr, const int* __restrict__ iptr,
                              const int* __restrict__ ideg, bf16* __restrict__ ri1) {
    int node = blockIdx.x * 4 + (threadIdx.x >> 6);
    int lane = threadIdx.x & 63;
    if (node >= NITEMS) return;
    int end = iptr[node], dg = ideg[node], j = end - dg;
    float a0 = 0.f, a1 = 0.f;
    for (; j + 1 < end; j += 2) {
        int s0 = csr[j], s1 = csr[j + 1];
        a0 += uemb[s0 * 64 + lane];
        a1 += uemb[s1 * 64 + lane];
    }
    if (j < end) a0 += uemb[csr[j] * 64 + lane];
    float dgf = (float)dg;
    float inv = 1.0f / fmaxf(dgf, 1.0f);
    float sw = 1.0f - dgf / (dgf + 1e-8f);
    float v = sw * iemb[node * 64 + lane] + (a0 + a1) * inv;
    ri1[node * 64 + lane] = __float2bfloat16(v);
}

// ---- soc1 = mean(uemb[social sources]); one wave per user ----
__global__ void k_gather_soc(const float* __restrict__ uemb,
                             const int* __restrict__ csr, const int* __restrict__ sptr,
                             const int* __restrict__ sdeg, bf16* __restrict__ soc1) {
    int node = blockIdx.x * 4 + (threadIdx.x >> 6);
    int lane = threadIdx.x & 63;
    if (node >= NUSERS) return;
    int end = sptr[node], dg = sdeg[node], j = end - dg;
    float a0 = 0.f, a1 = 0.f;
    for (; j + 1 < end; j += 2) {
        int s0 = csr[j], s1 = csr[j + 1];
        a0 += uemb[s0 * 64 + lane];
        a1 += uemb[s1 * 64 + lane];
    }
    if (j < end) a0 += uemb[csr[j] * 64 + lane];
    float inv = 1.0f / fmaxf((float)dg, 1.0f);
    soc1[node * 64 + lane] = __float2bfloat16((a0 + a1) * inv);
}

// ---- batch rating means: ru1c[b]=mean(iemb[li]), ru2c[b]=mean(ri1[li]) ----
__global__ void k_batch_rat(const int* __restrict__ users, const float* __restrict__ iemb,
                            const bf16* __restrict__ ri1, const int* __restrict__ csr,
                            const int* __restrict__ uptr, const int* __restrict__ udeg,
                            float* __restrict__ ru1c, float* __restrict__ ru2c) {
    int b = blockIdx.x * 4 + (threadIdx.x >> 6);
    int lane = threadIdx.x & 63;
    if (b >= NBATCH) return;
    int u = users[b];
    int end = uptr[u], dg = udeg[u];
    float a1 = 0.f, a2 = 0.f;
    for (int j = end - dg; j < end; ++j) {
        int it = csr[j];
        a1 += iemb[it * 64 + lane];
        a2 += __bfloat162float(ri1[it * 64 + lane]);
    }
    float inv = 1.0f / fmaxf((float)dg, 1.0f);
    ru1c[b * 64 + lane] = a1 * inv;
    ru2c[b * 64 + lane] = a2 * inv;
}

// ---- batch social mean: soc2c[b] = mean(soc1[srcs of users[b]]) ----
__global__ void k_batch_soc(const int* __restrict__ users, const bf16* __restrict__ soc1,
                            const int* __restrict__ csr, const int* __restrict__ sptr,
                            const int* __restrict__ sdeg, float* __restrict__ soc2c) {
    int b = blockIdx.x * 4 + (threadIdx.x >> 6);
    int lane = threadIdx.x & 63;
    if (b >= NBATCH) return;
    int u = users[b];
    int end = sptr[u], dg = sdeg[u];
    float a = 0.f;
    for (int j = end - dg; j < end; ++j)
        a += __bfloat162float(soc1[csr[j] * 64 + lane]);
    soc2c[b * 64 + lane] = a / fmaxf((float)dg, 1.0f);
}

// ---- epilogue: one wave per batch element ----
__global__ void k_out(const int* __restrict__ users, const int* __restrict__ items,
                      const float* __restrict__ uemb, const float* __restrict__ iemb,
                      const bf16* __restrict__ soc1, const float* __restrict__ ru1c,
                      const float* __restrict__ ru2c, const float* __restrict__ soc2c,
                      const int* __restrict__ udeg, float* __restrict__ out) {
    int b = blockIdx.x;
    int d = threadIdx.x;  // 0..63
    int u = users[b], it = items[b];
    float ud = (float)udeg[u];
    float usw = 1.0f - ud / (ud + 1e-8f);       // f32: 1 if deg==0 else 0
    float ue = uemb[u * 64 + d];
    float s1 = __bfloat162float(soc1[u * 64 + d]);
    float r1 = usw * ue + ru1c[b * 64 + d];
    float s2 = soc2c[b * 64 + d];
    float r2 = usw * r1 + ru2c[b * 64 + d];
    float fu = ue + 0.5f * (s1 + r1) + 0.5f * (s2 + r2);
    float iv = iemb[it * 64 + d];
    out[NBATCH + b * 64 + d]               = fu;
    out[NBATCH + NBATCH * 64 + b * 64 + d] = iv;
    float p = fu * iv;
    #pragma unroll
    for (int o = 32; o > 0; o >>= 1) p += __shfl_down(p, o);
    if (d == 0) out[b] = 1.0f / (1.0f + __expf(-p));
}

extern "C" void kernel_launch(void* const* d_in, const int* in_sizes, int n_in,
                              void* d_out, int out_size, void* d_ws, size_t ws_size,
                              hipStream_t stream) {
    const float* uemb  = (const float*)d_in[0];
    const float* iemb  = (const float*)d_in[1];
    const int*   users = (const int*)d_in[2];
    const int*   items = (const int*)d_in[3];
    const int*   ssrc  = (const int*)d_in[4];
    const int*   sdst  = (const int*)d_in[5];
    const int*   lu    = (const int*)d_in[6];
    const int*   li    = (const int*)d_in[7];
    float* out = (float*)d_out;

    if (ws_size < (size_t)WS_FLOATS * 4) return;  // would show absmax==0.5 diagnostic

    int*   W     = (int*)d_ws;
    int*   cur   = W + OFF_CUR;
    int*   ideg  = W + OFF_IDEG;
    int*   udeg  = W + OFF_UDEG;
    int*   sdeg  = W + OFF_SDEG;
    int*   iptr  = W + OFF_IPTR;
    int*   uptr  = W + OFF_UPTR;
    int*   sptr  = W + OFF_SPTR;
    float* ru1c  = (float*)(W + OFF_RU1C);
    float* ru2c  = (float*)(W + OFF_RU2C);
    float* soc2c = (float*)(W + OFF_SOC2C);
    int*   csrsd = W + OFF_CSRSD;
    int*   csrli = W + OFF_CSRLI;
    int*   csrlu = W + OFF_CSRLU;
    bf16*  ri1   = (bf16*)(W + OFF_RI1);
    bf16*  soc1  = (bf16*)(W + OFF_SOC1);   // overlays csrli/csrlu/ri1 (dead by then)

    hipMemsetAsync(d_ws, 0, (size_t)OFF_HEND * 4, stream);  // cursors + histograms

    const int B = 256;
    const int gE = (NEDGE + B - 1) / B;

    // CSR build
    k_hist<<<gE, B, 0, stream>>>(lu, li, sdst, udeg, ideg, sdeg);
    k_scan<<<(NITEMS + 255) / 256, 256, 0, stream>>>(ideg, iptr, NITEMS, cur + 0);
    k_scan<<<(NUSERS + 255) / 256, 256, 0, stream>>>(udeg, uptr, NUSERS, cur + 1);
    k_scan<<<(NUSERS + 255) / 256, 256, 0, stream>>>(sdeg, sptr, NUSERS, cur + 2);
    k_permute<<<gE, B, 0, stream>>>(lu, li, ssrc, sdst, iptr, uptr, sptr,
                                    csrli, csrlu, csrsd);

    // rating branch (gathers)
    k_gather_item<<<(NITEMS + 3) / 4, 256, 0, stream>>>(iemb, uemb, csrli, iptr, ideg, ri1);
    k_batch_rat<<<(NBATCH + 3) / 4, 256, 0, stream>>>(users, iemb, ri1, csrlu, uptr,
                                                      udeg, ru1c, ru2c);
    // social branch (csrsd untouched by the soc1 overlay)
    k_gather_soc<<<(NUSERS + 3) / 4, 256, 0, stream>>>(uemb, csrsd, sptr, sdeg, soc1);
    k_batch_soc<<<(NBATCH + 3) / 4, 256, 0, stream>>>(users, soc1, csrsd, sptr, sdeg, soc2c);

    // epilogue
    k_out<<<NBATCH, 64, 0, stream>>>(users, items, uemb, iemb, soc1, ru1c, ru2c,
                                     soc2c, udeg, out);
}

// Round 6
// 544.264 us; speedup vs baseline: 4.2564x; 1.2430x over previous
//
#include <hip/hip_runtime.h>
#include <hip/hip_bf16.h>

#define NUSERS 100000
#define NITEMS 50000
#define NEDGE  1000000
#define NBATCH 16384

// ---- workspace layout, units of 4 bytes (total 8,370,744 units = 33.5 MB) ----
// Overlay liveness: soc1 (3.2M units) overlays csrli+csrlu+ri1 (3.6M units),
// ALL dead before k_gather_soc runs. csrsd is in its own region (stays live).
#define OFF_CUR    0                         // 16 ints (3 scan cursors + pad)
#define OFF_IDEG   16                        // NITEMS int
#define OFF_UDEG   (OFF_IDEG + NITEMS)       // NUSERS int
#define OFF_SDEG   (OFF_UDEG + NUSERS)       // NUSERS int
#define OFF_NEED   (OFF_SDEG + NUSERS)       // NUSERS bytes = 25000 units
#define OFF_HEND   (OFF_NEED + NUSERS / 4)   // end of memset-0 region
#define OFF_SLOT   OFF_HEND                  // NUSERS int (memset 0xFF -> -1)
#define OFF_IPTR   (OFF_SLOT + NUSERS)       // NITEMS
#define OFF_UPTR   (OFF_IPTR + NITEMS)       // NUSERS
#define OFF_SPTR   (OFF_UPTR + NUSERS)       // NUSERS
#define OFF_RU1C   (OFF_SPTR + NUSERS)       // NBATCH*64 f32
#define OFF_RU2C   (OFF_RU1C + NBATCH * 64)
#define OFF_SOC2C  (OFF_RU2C + NBATCH * 64)
#define OFF_CSRSD  (OFF_SOC2C + NBATCH * 64) // NEDGE int (LIVE through social branch)
#define OFF_CSRLI  (OFF_CSRSD + NEDGE)       // NEDGE int (dead after gather_item)
#define OFF_CSRLU  (OFF_CSRLI + NEDGE)       // NEDGE int, batch-only segments (dead after batch_rat)
#define OFF_RI1    (OFF_CSRLU + NEDGE)       // NITEMS*32 units bf16 (dead after batch_rat)
#define OFF_SOC1   OFF_CSRLI                 // NUSERS*64 bf16 = 3.2M units overlay
#define WS_FLOATS  (OFF_RI1 + NITEMS * 32)   // 8,370,744

typedef __hip_bfloat16 bf16;

// ---- 3 histograms + slot map + batch needed-flags in one pass ----
__global__ void k_hist(const int* __restrict__ lu, const int* __restrict__ li,
                       const int* __restrict__ sd, int* __restrict__ udeg,
                       int* __restrict__ ideg, int* __restrict__ sdeg,
                       const int* __restrict__ users, int* __restrict__ slot,
                       unsigned char* __restrict__ needed) {
    int e = blockIdx.x * blockDim.x + threadIdx.x;
    if (e < NBATCH) {            // duplicate users: any winner fine (membership only)
        int u = users[e];
        slot[u] = e;
        needed[u] = 1;
    }
    if (e >= NEDGE) return;
    atomicAdd(&udeg[lu[e]], 1);
    atomicAdd(&ideg[li[e]], 1);
    atomicAdd(&sdeg[sd[e]], 1);
}

// ---- fused segment-start assignment for the 3 degree arrays.
//      Block-local exclusive scan + global cursor; segment order arbitrary. ----
#define NBI ((NITEMS + 255) / 256)   // 196
#define NBU ((NUSERS + 255) / 256)   // 391
__global__ void k_scan3(const int* __restrict__ ideg, const int* __restrict__ udeg,
                        const int* __restrict__ sdeg, int* __restrict__ iptr,
                        int* __restrict__ uptr, int* __restrict__ sptr,
                        int* __restrict__ cur) {
    __shared__ int s[256];
    __shared__ int sbase;
    int blk = blockIdx.x, lb, n;
    const int* deg; int* ptr; int* cursor;
    if (blk < NBI)            { deg = ideg; ptr = iptr; n = NITEMS; cursor = cur + 0; lb = blk; }
    else if (blk < NBI + NBU) { deg = udeg; ptr = uptr; n = NUSERS; cursor = cur + 1; lb = blk - NBI; }
    else                      { deg = sdeg; ptr = sptr; n = NUSERS; cursor = cur + 2; lb = blk - NBI - NBU; }
    int g = lb * 256 + threadIdx.x;
    int v = (g < n) ? deg[g] : 0;
    s[threadIdx.x] = v;
    __syncthreads();
    for (int o = 1; o < 256; o <<= 1) {
        int t = (threadIdx.x >= (unsigned)o) ? s[threadIdx.x - o] : 0;
        __syncthreads();
        s[threadIdx.x] += t;
        __syncthreads();
    }
    if (threadIdx.x == 255) sbase = atomicAdd(cursor, s[255]);
    __syncthreads();
    if (g < n) ptr[g] = sbase + s[threadIdx.x] - v;   // exclusive start
}

// ---- permute edges into CSRs. csrlu restricted to batch users; also marks
//      social sources of batch users as needed. ----
__global__ void k_permute(const int* __restrict__ lu, const int* __restrict__ li,
                          const int* __restrict__ ssrc, const int* __restrict__ sdst,
                          const int* __restrict__ slot, int* __restrict__ iptr,
                          int* __restrict__ uptr, int* __restrict__ sptr,
                          int* __restrict__ csr_li, int* __restrict__ csr_lu,
                          int* __restrict__ csr_sd, unsigned char* __restrict__ needed) {
    int e = blockIdx.x * blockDim.x + threadIdx.x;
    if (e >= NEDGE) return;
    int a = lu[e], b = li[e];
    csr_li[atomicAdd(&iptr[b], 1)] = a;                 // item <- liking users (full)
    if (slot[a] >= 0) csr_lu[atomicAdd(&uptr[a], 1)] = b;  // user <- items, batch only
    int s = ssrc[e], d = sdst[e];
    csr_sd[atomicAdd(&sptr[d], 1)] = s;                 // user <- social sources (full)
    if (slot[d] >= 0) needed[s] = 1;                    // soc1 needed at s
}

// ---- ri1 = i_sw*iemb + mean(uemb[liking users]); one wave per item ----
__global__ void k_gather_item(const float* __restrict__ iemb,
                              const float* __restrict__ uemb,
                              const int* __restrict__ csr, const int* __restrict__ iptr,
                              const int* __restrict__ ideg, bf16* __restrict__ ri1) {
    int node = blockIdx.x * 4 + (threadIdx.x >> 6);
    int lane = threadIdx.x & 63;
    if (node >= NITEMS) return;
    int end = iptr[node], dg = ideg[node], j = end - dg;
    float a0 = 0.f, a1 = 0.f;
    for (; j + 1 < end; j += 2) {
        int s0 = csr[j], s1 = csr[j + 1];
        a0 += uemb[s0 * 64 + lane];
        a1 += uemb[s1 * 64 + lane];
    }
    if (j < end) a0 += uemb[csr[j] * 64 + lane];
    float dgf = (float)dg;
    float inv = 1.0f / fmaxf(dgf, 1.0f);
    float sw = 1.0f - dgf / (dgf + 1e-8f);
    float v = sw * iemb[node * 64 + lane] + (a0 + a1) * inv;
    ri1[node * 64 + lane] = __float2bfloat16(v);
}

// ---- soc1 = mean(uemb[social sources]); only where needed ----
__global__ void k_gather_soc(const float* __restrict__ uemb,
                             const int* __restrict__ csr, const int* __restrict__ sptr,
                             const int* __restrict__ sdeg,
                             const unsigned char* __restrict__ needed,
                             bf16* __restrict__ soc1) {
    int node = blockIdx.x * 4 + (threadIdx.x >> 6);
    int lane = threadIdx.x & 63;
    if (node >= NUSERS) return;
    if (!needed[node]) return;   // soc1 row never read -> skip (row left as garbage)
    int end = sptr[node], dg = sdeg[node], j = end - dg;
    float a0 = 0.f, a1 = 0.f;
    for (; j + 1 < end; j += 2) {
        int s0 = csr[j], s1 = csr[j + 1];
        a0 += uemb[s0 * 64 + lane];
        a1 += uemb[s1 * 64 + lane];
    }
    if (j < end) a0 += uemb[csr[j] * 64 + lane];
    float inv = 1.0f / fmaxf((float)dg, 1.0f);
    soc1[node * 64 + lane] = __float2bfloat16((a0 + a1) * inv);
}

// ---- batch rating means: ru1c[b]=mean(iemb[li]), ru2c[b]=mean(ri1[li]) ----
__global__ void k_batch_rat(const int* __restrict__ users, const float* __restrict__ iemb,
                            const bf16* __restrict__ ri1, const int* __restrict__ csr,
                            const int* __restrict__ uptr, const int* __restrict__ udeg,
                            float* __restrict__ ru1c, float* __restrict__ ru2c) {
    int b = blockIdx.x * 4 + (threadIdx.x >> 6);
    int lane = threadIdx.x & 63;
    if (b >= NBATCH) return;
    int u = users[b];
    int end = uptr[u], dg = udeg[u];
    float a1 = 0.f, a2 = 0.f;
    for (int j = end - dg; j < end; ++j) {
        int it = csr[j];
        a1 += iemb[it * 64 + lane];
        a2 += __bfloat162float(ri1[it * 64 + lane]);
    }
    float inv = 1.0f / fmaxf((float)dg, 1.0f);
    ru1c[b * 64 + lane] = a1 * inv;
    ru2c[b * 64 + lane] = a2 * inv;
}

// ---- batch social mean: soc2c[b] = mean(soc1[srcs of users[b]]) ----
__global__ void k_batch_soc(const int* __restrict__ users, const bf16* __restrict__ soc1,
                            const int* __restrict__ csr, const int* __restrict__ sptr,
                            const int* __restrict__ sdeg, float* __restrict__ soc2c) {
    int b = blockIdx.x * 4 + (threadIdx.x >> 6);
    int lane = threadIdx.x & 63;
    if (b >= NBATCH) return;
    int u = users[b];
    int end = sptr[u], dg = sdeg[u];
    float a = 0.f;
    for (int j = end - dg; j < end; ++j)
        a += __bfloat162float(soc1[csr[j] * 64 + lane]);
    soc2c[b * 64 + lane] = a / fmaxf((float)dg, 1.0f);
}

// ---- epilogue: one wave per batch element ----
__global__ void k_out(const int* __restrict__ users, const int* __restrict__ items,
                      const float* __restrict__ uemb, const float* __restrict__ iemb,
                      const bf16* __restrict__ soc1, const float* __restrict__ ru1c,
                      const float* __restrict__ ru2c, const float* __restrict__ soc2c,
                      const int* __restrict__ udeg, float* __restrict__ out) {
    int b = blockIdx.x;
    int d = threadIdx.x;  // 0..63
    int u = users[b], it = items[b];
    float ud = (float)udeg[u];
    float usw = 1.0f - ud / (ud + 1e-8f);       // f32: 1 if deg==0 else 0
    float ue = uemb[u * 64 + d];
    float s1 = __bfloat162float(soc1[u * 64 + d]);
    float r1 = usw * ue + ru1c[b * 64 + d];
    float s2 = soc2c[b * 64 + d];
    float r2 = usw * r1 + ru2c[b * 64 + d];
    float fu = ue + 0.5f * (s1 + r1) + 0.5f * (s2 + r2);
    float iv = iemb[it * 64 + d];
    out[NBATCH + b * 64 + d]               = fu;
    out[NBATCH + NBATCH * 64 + b * 64 + d] = iv;
    float p = fu * iv;
    #pragma unroll
    for (int o = 32; o > 0; o >>= 1) p += __shfl_down(p, o);
    if (d == 0) out[b] = 1.0f / (1.0f + __expf(-p));
}

extern "C" void kernel_launch(void* const* d_in, const int* in_sizes, int n_in,
                              void* d_out, int out_size, void* d_ws, size_t ws_size,
                              hipStream_t stream) {
    const float* uemb  = (const float*)d_in[0];
    const float* iemb  = (const float*)d_in[1];
    const int*   users = (const int*)d_in[2];
    const int*   items = (const int*)d_in[3];
    const int*   ssrc  = (const int*)d_in[4];
    const int*   sdst  = (const int*)d_in[5];
    const int*   lu    = (const int*)d_in[6];
    const int*   li    = (const int*)d_in[7];
    float* out = (float*)d_out;

    if (ws_size < (size_t)WS_FLOATS * 4) return;  // would show absmax==0.5 diagnostic

    int*           W      = (int*)d_ws;
    int*           cur    = W + OFF_CUR;
    int*           ideg   = W + OFF_IDEG;
    int*           udeg   = W + OFF_UDEG;
    int*           sdeg   = W + OFF_SDEG;
    unsigned char* needed = (unsigned char*)(W + OFF_NEED);
    int*           slot   = W + OFF_SLOT;
    int*           iptr   = W + OFF_IPTR;
    int*           uptr   = W + OFF_UPTR;
    int*           sptr   = W + OFF_SPTR;
    float*         ru1c   = (float*)(W + OFF_RU1C);
    float*         ru2c   = (float*)(W + OFF_RU2C);
    float*         soc2c  = (float*)(W + OFF_SOC2C);
    int*           csrsd  = W + OFF_CSRSD;
    int*           csrli  = W + OFF_CSRLI;
    int*           csrlu  = W + OFF_CSRLU;
    bf16*          ri1    = (bf16*)(W + OFF_RI1);
    bf16*          soc1   = (bf16*)(W + OFF_SOC1);  // overlays csrli/csrlu/ri1

    hipMemsetAsync(d_ws, 0, (size_t)OFF_HEND * 4, stream);   // cur + hists + needed
    hipMemsetAsync(slot, 0xFF, (size_t)NUSERS * 4, stream);  // slot = -1

    const int B = 256;
    const int gE = (NEDGE + B - 1) / B;

    // CSR build
    k_hist<<<gE, B, 0, stream>>>(lu, li, sdst, udeg, ideg, sdeg, users, slot, needed);
    k_scan3<<<NBI + 2 * NBU, 256, 0, stream>>>(ideg, udeg, sdeg, iptr, uptr, sptr, cur);
    k_permute<<<gE, B, 0, stream>>>(lu, li, ssrc, sdst, slot, iptr, uptr, sptr,
                                    csrli, csrlu, csrsd, needed);

    // rating branch (gathers)
    k_gather_item<<<(NITEMS + 3) / 4, 256, 0, stream>>>(iemb, uemb, csrli, iptr, ideg, ri1);
    k_batch_rat<<<(NBATCH + 3) / 4, 256, 0, stream>>>(users, iemb, ri1, csrlu, uptr,
                                                      udeg, ru1c, ru2c);
    // social branch (csrsd untouched by the soc1 overlay)
    k_gather_soc<<<(NUSERS + 3) / 4, 256, 0, stream>>>(uemb, csrsd, sptr, sdeg, needed, soc1);
    k_batch_soc<<<(NBATCH + 3) / 4, 256, 0, stream>>>(users, soc1, csrsd, sptr, sdeg, soc2c);

    // epilogue
    k_out<<<NBATCH, 64, 0, stream>>>(users, items, uemb, iemb, soc1, ru1c, ru2c,
                                     soc2c, udeg, out);
}

// Round 7
// 491.459 us; speedup vs baseline: 4.7137x; 1.1074x over previous
//
#include <hip/hip_runtime.h>
#include <hip/hip_bf16.h>

#define NUSERS 100000
#define NITEMS 50000
#define NEDGE  1000000
#define NBATCH 16384

// ---- workspace layout, units of 4 bytes (total 7,322,168 units = 29.3 MB) ----
// Overlay liveness: soc1 (3.2M units) overlays csrli+csrlu+ri1 (3.6M units),
// ALL dead before k_gather_soc runs. csrsd is in its own region (stays live).
#define OFF_CUR    0                         // 16 ints (3 scan cursors + pad)
#define OFF_IDEG   16                        // NITEMS int
#define OFF_UDEG   (OFF_IDEG + NITEMS)       // NUSERS int (batch users only)
#define OFF_SDEG   (OFF_UDEG + NUSERS)       // NUSERS int
#define OFF_NEED   (OFF_SDEG + NUSERS)       // NUSERS bytes = 25000 units
#define OFF_HEND   (OFF_NEED + NUSERS / 4)   // end of memset-0 region
#define OFF_SLOT   OFF_HEND                  // NUSERS int (memset 0xFF -> -1)
#define OFF_IPTR   (OFF_SLOT + NUSERS)       // NITEMS
#define OFF_UPTR   (OFF_IPTR + NITEMS)       // NUSERS
#define OFF_SPTR   (OFF_UPTR + NUSERS)       // NUSERS
#define OFF_RU1C   (OFF_SPTR + NUSERS)       // NBATCH*64 f32
#define OFF_RU2C   (OFF_RU1C + NBATCH * 64)  // NBATCH*64 f32
#define OFF_CSRSD  (OFF_RU2C + NBATCH * 64)  // NEDGE int (LIVE through social branch)
#define OFF_CSRLI  (OFF_CSRSD + NEDGE)       // NEDGE int (dead after gather_item)
#define OFF_CSRLU  (OFF_CSRLI + NEDGE)       // NEDGE int, batch-only (dead after batch_rat)
#define OFF_RI1    (OFF_CSRLU + NEDGE)       // NITEMS*32 units bf16 (dead after batch_rat)
#define OFF_SOC1   OFF_CSRLI                 // NUSERS*64 bf16 = 3.2M units overlay
#define WS_FLOATS  (OFF_RI1 + NITEMS * 32)   // 7,322,168

typedef __hip_bfloat16 bf16;

// ---- tiny prepass: batch membership ----
__global__ void k_slot(const int* __restrict__ users, int* __restrict__ slot,
                       unsigned char* __restrict__ needed) {
    int b = blockIdx.x * blockDim.x + threadIdx.x;
    if (b < NBATCH) {            // duplicate users: any winner fine (membership only)
        int u = users[b];
        slot[u] = b;
        needed[u] = 1;
    }
}

// ---- histograms (udeg filtered to batch users) + needed marks ----
__global__ void k_hist(const int* __restrict__ lu, const int* __restrict__ li,
                       const int* __restrict__ sd, const int* __restrict__ ss,
                       const int* __restrict__ slot, int* __restrict__ udeg,
                       int* __restrict__ ideg, int* __restrict__ sdeg,
                       unsigned char* __restrict__ needed) {
    int e = blockIdx.x * blockDim.x + threadIdx.x;
    if (e >= NEDGE) return;
    int a = lu[e];
    if (slot[a] >= 0) atomicAdd(&udeg[a], 1);   // udeg only read at batch users
    atomicAdd(&ideg[li[e]], 1);
    int d = sd[e];
    atomicAdd(&sdeg[d], 1);
    if (slot[d] >= 0) needed[ss[e]] = 1;        // soc1 needed at sources of batch dsts
}

// ---- fused segment-start assignment for the 3 degree arrays ----
#define NBI ((NITEMS + 255) / 256)   // 196
#define NBU ((NUSERS + 255) / 256)   // 391
__global__ void k_scan3(const int* __restrict__ ideg, const int* __restrict__ udeg,
                        const int* __restrict__ sdeg, int* __restrict__ iptr,
                        int* __restrict__ uptr, int* __restrict__ sptr,
                        int* __restrict__ cur) {
    __shared__ int s[256];
    __shared__ int sbase;
    int blk = blockIdx.x, lb, n;
    const int* deg; int* ptr; int* cursor;
    if (blk < NBI)            { deg = ideg; ptr = iptr; n = NITEMS; cursor = cur + 0; lb = blk; }
    else if (blk < NBI + NBU) { deg = udeg; ptr = uptr; n = NUSERS; cursor = cur + 1; lb = blk - NBI; }
    else                      { deg = sdeg; ptr = sptr; n = NUSERS; cursor = cur + 2; lb = blk - NBI - NBU; }
    int g = lb * 256 + threadIdx.x;
    int v = (g < n) ? deg[g] : 0;
    s[threadIdx.x] = v;
    __syncthreads();
    for (int o = 1; o < 256; o <<= 1) {
        int t = (threadIdx.x >= (unsigned)o) ? s[threadIdx.x - o] : 0;
        __syncthreads();
        s[threadIdx.x] += t;
        __syncthreads();
    }
    if (threadIdx.x == 255) sbase = atomicAdd(cursor, s[255]);
    __syncthreads();
    if (g < n) ptr[g] = sbase + s[threadIdx.x] - v;   // exclusive start
}

// ---- permute edges into CSRs (csrlu: batch users; csrsd: needed dsts) ----
__global__ void k_permute(const int* __restrict__ lu, const int* __restrict__ li,
                          const int* __restrict__ ssrc, const int* __restrict__ sdst,
                          const int* __restrict__ slot,
                          const unsigned char* __restrict__ needed,
                          int* __restrict__ iptr, int* __restrict__ uptr,
                          int* __restrict__ sptr, int* __restrict__ csr_li,
                          int* __restrict__ csr_lu, int* __restrict__ csr_sd) {
    int e = blockIdx.x * blockDim.x + threadIdx.x;
    if (e >= NEDGE) return;
    int a = lu[e], b = li[e];
    csr_li[atomicAdd(&iptr[b], 1)] = a;                    // item <- liking users (full)
    if (slot[a] >= 0) csr_lu[atomicAdd(&uptr[a], 1)] = b;  // user <- items, batch only
    int s = ssrc[e], d = sdst[e];
    if (needed[d]) csr_sd[atomicAdd(&sptr[d], 1)] = s;     // only needed destinations
}

// ---- ri1 = i_sw*iemb + mean(uemb[liking users]); one wave per item ----
__global__ void k_gather_item(const float* __restrict__ iemb,
                              const float* __restrict__ uemb,
                              const int* __restrict__ csr, const int* __restrict__ iptr,
                              const int* __restrict__ ideg, bf16* __restrict__ ri1) {
    int node = blockIdx.x * 4 + (threadIdx.x >> 6);
    int lane = threadIdx.x & 63;
    if (node >= NITEMS) return;
    int end = iptr[node], dg = ideg[node], j = end - dg;
    float a0 = 0.f, a1 = 0.f;
    for (; j + 1 < end; j += 2) {
        int s0 = csr[j], s1 = csr[j + 1];
        a0 += uemb[s0 * 64 + lane];
        a1 += uemb[s1 * 64 + lane];
    }
    if (j < end) a0 += uemb[csr[j] * 64 + lane];
    float dgf = (float)dg;
    float inv = 1.0f / fmaxf(dgf, 1.0f);
    float sw = 1.0f - dgf / (dgf + 1e-8f);
    float v = sw * iemb[node * 64 + lane] + (a0 + a1) * inv;
    ri1[node * 64 + lane] = __float2bfloat16(v);
}

// ---- soc1 = mean(uemb[social sources]); only where needed ----
__global__ void k_gather_soc(const float* __restrict__ uemb,
                             const int* __restrict__ csr, const int* __restrict__ sptr,
                             const int* __restrict__ sdeg,
                             const unsigned char* __restrict__ needed,
                             bf16* __restrict__ soc1) {
    int node = blockIdx.x * 4 + (threadIdx.x >> 6);
    int lane = threadIdx.x & 63;
    if (node >= NUSERS) return;
    if (!needed[node]) return;   // row never read -> skip
    int end = sptr[node], dg = sdeg[node], j = end - dg;
    float a0 = 0.f, a1 = 0.f;
    for (; j + 1 < end; j += 2) {
        int s0 = csr[j], s1 = csr[j + 1];
        a0 += uemb[s0 * 64 + lane];
        a1 += uemb[s1 * 64 + lane];
    }
    if (j < end) a0 += uemb[csr[j] * 64 + lane];
    float inv = 1.0f / fmaxf((float)dg, 1.0f);
    soc1[node * 64 + lane] = __float2bfloat16((a0 + a1) * inv);
}

// ---- batch rating means: ru1c[b]=mean(iemb[li]), ru2c[b]=mean(ri1[li]) ----
__global__ void k_batch_rat(const int* __restrict__ users, const float* __restrict__ iemb,
                            const bf16* __restrict__ ri1, const int* __restrict__ csr,
                            const int* __restrict__ uptr, const int* __restrict__ udeg,
                            float* __restrict__ ru1c, float* __restrict__ ru2c) {
    int b = blockIdx.x * 4 + (threadIdx.x >> 6);
    int lane = threadIdx.x & 63;
    if (b >= NBATCH) return;
    int u = users[b];
    int end = uptr[u], dg = udeg[u];
    float a1 = 0.f, a2 = 0.f;
    for (int j = end - dg; j < end; ++j) {
        int it = csr[j];
        a1 += iemb[it * 64 + lane];
        a2 += __bfloat162float(ri1[it * 64 + lane]);
    }
    float inv = 1.0f / fmaxf((float)dg, 1.0f);
    ru1c[b * 64 + lane] = a1 * inv;
    ru2c[b * 64 + lane] = a2 * inv;
}

// ---- fused batch social mean + epilogue: 4 waves/block, wave per batch elem ----
__global__ void k_final(const int* __restrict__ users, const int* __restrict__ items,
                        const float* __restrict__ uemb, const float* __restrict__ iemb,
                        const bf16* __restrict__ soc1, const int* __restrict__ csr,
                        const int* __restrict__ sptr, const int* __restrict__ sdeg,
                        const float* __restrict__ ru1c, const float* __restrict__ ru2c,
                        const int* __restrict__ udeg, float* __restrict__ out) {
    int b = blockIdx.x * 4 + (threadIdx.x >> 6);
    int d = threadIdx.x & 63;
    if (b >= NBATCH) return;
    int u = users[b], it = items[b];
    // soc2 = mean of soc1 over social sources of u
    int end = sptr[u], dg = sdeg[u];
    float a = 0.f;
    for (int j = end - dg; j < end; ++j)
        a += __bfloat162float(soc1[csr[j] * 64 + d]);
    float s2 = a / fmaxf((float)dg, 1.0f);
    // final combine
    float ud = (float)udeg[u];
    float usw = 1.0f - ud / (ud + 1e-8f);       // f32: 1 if deg==0 else 0
    float ue = uemb[u * 64 + d];
    float s1 = __bfloat162float(soc1[u * 64 + d]);
    float r1 = usw * ue + ru1c[b * 64 + d];
    float r2 = usw * r1 + ru2c[b * 64 + d];
    float fu = ue + 0.5f * (s1 + r1) + 0.5f * (s2 + r2);
    float iv = iemb[it * 64 + d];
    out[NBATCH + b * 64 + d]               = fu;
    out[NBATCH + NBATCH * 64 + b * 64 + d] = iv;
    float p = fu * iv;
    #pragma unroll
    for (int o = 32; o > 0; o >>= 1) p += __shfl_down(p, o);
    if (d == 0) out[b] = 1.0f / (1.0f + __expf(-p));
}

extern "C" void kernel_launch(void* const* d_in, const int* in_sizes, int n_in,
                              void* d_out, int out_size, void* d_ws, size_t ws_size,
                              hipStream_t stream) {
    const float* uemb  = (const float*)d_in[0];
    const float* iemb  = (const float*)d_in[1];
    const int*   users = (const int*)d_in[2];
    const int*   items = (const int*)d_in[3];
    const int*   ssrc  = (const int*)d_in[4];
    const int*   sdst  = (const int*)d_in[5];
    const int*   lu    = (const int*)d_in[6];
    const int*   li    = (const int*)d_in[7];
    float* out = (float*)d_out;

    if (ws_size < (size_t)WS_FLOATS * 4) return;  // would show absmax==0.5 diagnostic

    int*           W      = (int*)d_ws;
    int*           cur    = W + OFF_CUR;
    int*           ideg   = W + OFF_IDEG;
    int*           udeg   = W + OFF_UDEG;
    int*           sdeg   = W + OFF_SDEG;
    unsigned char* needed = (unsigned char*)(W + OFF_NEED);
    int*           slot   = W + OFF_SLOT;
    int*           iptr   = W + OFF_IPTR;
    int*           uptr   = W + OFF_UPTR;
    int*           sptr   = W + OFF_SPTR;
    float*         ru1c   = (float*)(W + OFF_RU1C);
    float*         ru2c   = (float*)(W + OFF_RU2C);
    int*           csrsd  = W + OFF_CSRSD;
    int*           csrli  = W + OFF_CSRLI;
    int*           csrlu  = W + OFF_CSRLU;
    bf16*          ri1    = (bf16*)(W + OFF_RI1);
    bf16*          soc1   = (bf16*)(W + OFF_SOC1);  // overlays csrli/csrlu/ri1

    hipMemsetAsync(d_ws, 0, (size_t)OFF_HEND * 4, stream);   // cur + hists + needed
    hipMemsetAsync(slot, 0xFF, (size_t)NUSERS * 4, stream);  // slot = -1

    const int B = 256;
    const int gE = (NEDGE + B - 1) / B;

    // CSR build
    k_slot<<<(NBATCH + B - 1) / B, B, 0, stream>>>(users, slot, needed);
    k_hist<<<gE, B, 0, stream>>>(lu, li, sdst, ssrc, slot, udeg, ideg, sdeg, needed);
    k_scan3<<<NBI + 2 * NBU, 256, 0, stream>>>(ideg, udeg, sdeg, iptr, uptr, sptr, cur);
    k_permute<<<gE, B, 0, stream>>>(lu, li, ssrc, sdst, slot, needed,
                                    iptr, uptr, sptr, csrli, csrlu, csrsd);

    // rating branch
    k_gather_item<<<(NITEMS + 3) / 4, 256, 0, stream>>>(iemb, uemb, csrli, iptr, ideg, ri1);
    k_batch_rat<<<(NBATCH + 3) / 4, 256, 0, stream>>>(users, iemb, ri1, csrlu, uptr,
                                                      udeg, ru1c, ru2c);
    // social branch (csrsd untouched by the soc1 overlay)
    k_gather_soc<<<(NUSERS + 3) / 4, 256, 0, stream>>>(uemb, csrsd, sptr, sdeg, needed, soc1);

    // fused batch social mean + epilogue
    k_final<<<(NBATCH + 3) / 4, 256, 0, stream>>>(users, items, uemb, iemb, soc1,
                                                  csrsd, sptr, sdeg, ru1c, ru2c, udeg, out);
}

// Round 8
// 473.363 us; speedup vs baseline: 4.8939x; 1.0382x over previous
//
#include <hip/hip_runtime.h>
#include <hip/hip_bf16.h>

#define NUSERS 100000
#define NITEMS 50000
#define NEDGE  1000000
#define NBATCH 16384
#define CAP_LU 320000     // filtered like-edges of batch users; expected ~151K (2x margin)

// ---- workspace layout, units of 4 bytes; total 8,964,456 units = 35.86 MB ----
#define OFF_GC     0                          // 3*256 bucket counts (memset 0)
#define OFF_GB     768                        // 3*256 bucket bases
#define OFF_GCUR   1536                       // 3*256 bucket cursors
#define OFF_NEED   2304                       // NUSERS bytes = 25000 units (memset 0)
#define OFF_ZEND   (OFF_NEED + NUSERS / 4)    // 27,304 end of memset-0 region
#define OFF_SLOT   OFF_ZEND                   // NUSERS int (memset 0xFF)
#define OFF_IDEG   (OFF_SLOT + NUSERS)
#define OFF_UDEG   (OFF_IDEG + NITEMS)
#define OFF_SDEG   (OFF_UDEG + NUSERS)
#define OFF_ISTART (OFF_SDEG + NUSERS)
#define OFF_USTART (OFF_ISTART + NITEMS)
#define OFF_SSTART (OFF_USTART + NUSERS)
#define OFF_PARTLI (OFF_SSTART + NUSERS)      // 627,304; NEDGE (dead after passD)
#define OFF_PARTLU (OFF_PARTLI + NEDGE)       // CAP_LU  (dead after passD)
#define OFF_PARTSD (OFF_PARTLU + CAP_LU)      // NEDGE   (dead after passD)
#define OFF_CSRLI  (OFF_PARTSD + NEDGE)       // NEDGE   (dead after gather_item)
#define OFF_CSRLU  (OFF_CSRLI + NEDGE)        // CAP_LU  (live till batch_rat)
#define OFF_RI1    (OFF_CSRLU + CAP_LU)       // NITEMS*32 bf16 (live till batch_rat)
#define OFF_CSRSD  (OFF_RI1 + NITEMS * 32)    // NEDGE (live till k_final)
#define OFF_RU1C   (OFF_CSRSD + NEDGE)        // NBATCH*64 f32
#define OFF_RU2C   (OFF_RU1C + NBATCH * 64)   // NBATCH*64 f32
#define WS_FLOATS  (OFF_RU2C + NBATCH * 64)   // 8,964,456
// soc1 (NUSERS*64 bf16 = 3.2M units) overlays partLI+partLU+partSD+head of csrli
// = [627,304 .. 3,827,304) < OFF_CSRLU (3,947,304). All dead before gather_soc.
#define OFF_SOC1   OFF_PARTLI

typedef __hip_bfloat16 bf16;

// ---- batch membership ----
__global__ void k_slot(const int* __restrict__ users, int* __restrict__ slot,
                       unsigned char* __restrict__ needed) {
    int b = blockIdx.x * blockDim.x + threadIdx.x;
    if (b < NBATCH) {
        int u = users[b];
        slot[u] = b;          // duplicate users: any winner fine (membership only)
        needed[u] = 1;
    }
}

// ---- pass A: per-block LDS bucket histograms -> global bucket counts;
//      also mark needed[] (social sources of batch destinations) ----
__global__ void k_passA(const int* __restrict__ lu, const int* __restrict__ li,
                        const int* __restrict__ sd, const int* __restrict__ ss,
                        const int* __restrict__ slot, int* __restrict__ gcnt,
                        unsigned char* __restrict__ needed) {
    __shared__ int lc[768];
    int t = threadIdx.x;
    for (int k = t; k < 768; k += 256) lc[k] = 0;
    __syncthreads();
    int e = blockIdx.x * 256 + t;
    if (e < NEDGE) {
        int item = li[e], a = lu[e], d = sd[e];
        atomicAdd(&lc[item >> 9], 1);                       // list0: csrli (by item)
        if (slot[a] >= 0) atomicAdd(&lc[256 + (a >> 9)], 1);// list1: csrlu (batch users)
        atomicAdd(&lc[512 + (d >> 9)], 1);                  // list2: csrsd (by dst user)
        if (slot[d] >= 0) needed[ss[e]] = 1;                // soc1 needed at source
    }
    __syncthreads();
    for (int k = t; k < 768; k += 256)
        if (lc[k]) atomicAdd(&gcnt[k], lc[k]);
}

// ---- pass B: one block; 3 exclusive scans of 256 bucket counts ----
__global__ void k_passB(const int* __restrict__ gcnt, int* __restrict__ gbase,
                        int* __restrict__ gcur) {
    __shared__ int s[256];
    int t = threadIdx.x;
    for (int j = 0; j < 3; ++j) {
        int v = gcnt[j * 256 + t];
        s[t] = v;
        __syncthreads();
        for (int o = 1; o < 256; o <<= 1) {
            int x = (t >= o) ? s[t - o] : 0;
            __syncthreads();
            s[t] += x;
            __syncthreads();
        }
        int ex = s[t] - v;
        gbase[j * 256 + t] = ex;
        gcur[j * 256 + t] = ex;
        __syncthreads();
    }
}

// ---- pass C: partition edges into per-bucket chunks (packed u32) ----
__global__ void k_passC(const int* __restrict__ lu, const int* __restrict__ li,
                        const int* __restrict__ sd, const int* __restrict__ ss,
                        const int* __restrict__ slot, int* __restrict__ gcur,
                        int* __restrict__ partLI, int* __restrict__ partLU,
                        int* __restrict__ partSD) {
    __shared__ int lc[768];   // local counts, then rank counters
    __shared__ int go[768];   // this block's global chunk offsets
    int t = threadIdx.x;
    for (int k = t; k < 768; k += 256) lc[k] = 0;
    __syncthreads();
    int e = blockIdx.x * 256 + t;
    int item = 0, a = 0, d = 0, s_ = 0, live = (e < NEDGE), doLU = 0;
    if (live) {
        item = li[e]; a = lu[e]; d = sd[e]; s_ = ss[e];
        atomicAdd(&lc[item >> 9], 1);
        doLU = (slot[a] >= 0);
        if (doLU) atomicAdd(&lc[256 + (a >> 9)], 1);
        atomicAdd(&lc[512 + (d >> 9)], 1);
    }
    __syncthreads();
    for (int k = t; k < 768; k += 256) {
        go[k] = lc[k] ? atomicAdd(&gcur[k], lc[k]) : 0;
        lc[k] = 0;
    }
    __syncthreads();
    if (live) {
        int b0 = item >> 9;
        int r0 = atomicAdd(&lc[b0], 1);
        partLI[go[b0] + r0] = (a << 9) | (item & 511);
        if (doLU) {
            int b1 = 256 + (a >> 9);
            int r1 = atomicAdd(&lc[b1], 1);
            partLU[go[b1] + r1] = (item << 9) | (a & 511);
        }
        int b2 = 512 + (d >> 9);
        int r2 = atomicAdd(&lc[b2], 1);
        partSD[go[b2] + r2] = (s_ << 9) | (d & 511);
    }
}

// ---- pass D: one block per bucket; local count/scan -> deg/start (coalesced)
//      + rank-scatter CSR values into the bucket's compact window ----
__global__ void k_passD(const int* __restrict__ gcnt, const int* __restrict__ gbase,
                        const int* __restrict__ partLI, const int* __restrict__ partLU,
                        const int* __restrict__ partSD, int* __restrict__ csrli,
                        int* __restrict__ csrlu, int* __restrict__ csrsd,
                        int* __restrict__ ideg, int* __restrict__ udeg,
                        int* __restrict__ sdeg, int* __restrict__ istart,
                        int* __restrict__ ustart, int* __restrict__ sstart) {
    __shared__ int lcnt[512], lstart[512], sb[2][512];
    int t = threadIdx.x;
    int blk = blockIdx.x, list, b;
    const int* part; int* csr; int* deg; int* start; int n;
    if (blk < 196)      { list = 0; b = blk;       part = partLI; csr = csrli; deg = ideg; start = istart; n = NITEMS; }
    else if (blk < 392) { list = 1; b = blk - 196; part = partLU; csr = csrlu; deg = udeg; start = ustart; n = NUSERS; }
    else                { list = 2; b = blk - 392; part = partSD; csr = csrsd; deg = sdeg; start = sstart; n = NUSERS; }
    int base = gbase[list * 256 + b], cnt = gcnt[list * 256 + b];
    int node0 = b << 9;
    int M = n - node0; if (M > 512) M = 512; if (M < 0) M = 0;

    lcnt[t] = 0; lcnt[t + 256] = 0;
    __syncthreads();
    for (int i = t; i < cnt; i += 256) atomicAdd(&lcnt[part[base + i] & 511], 1);
    __syncthreads();
    sb[0][t] = lcnt[t]; sb[0][t + 256] = lcnt[t + 256];
    __syncthreads();
    int pp = 0;
    for (int o = 1; o < 512; o <<= 1) {
        int np = pp ^ 1;
        for (int k = t; k < 512; k += 256) {
            int v = sb[pp][k];
            if (k >= o) v += sb[pp][k - o];
            sb[np][k] = v;
        }
        __syncthreads();
        pp = np;
    }
    for (int k = t; k < 512; k += 256) {
        int ex = sb[pp][k] - lcnt[k];       // exclusive scan
        lstart[k] = ex;
        if (k < M) { deg[node0 + k] = lcnt[k]; start[node0 + k] = base + ex; }
    }
    __syncthreads();
    lcnt[t] = 0; lcnt[t + 256] = 0;
    __syncthreads();
    for (int i = t; i < cnt; i += 256) {
        int p = part[base + i];
        int nl = p & 511;
        int r = atomicAdd(&lcnt[nl], 1);
        csr[base + lstart[nl] + r] = p >> 9;  // window stays in one XCD's L2
    }
}

// ---- ri1 = i_sw*iemb + mean(uemb[liking users]); one wave per item ----
__global__ void k_gather_item(const float* __restrict__ iemb,
                              const float* __restrict__ uemb,
                              const int* __restrict__ csr, const int* __restrict__ istart,
                              const int* __restrict__ ideg, bf16* __restrict__ ri1) {
    int node = blockIdx.x * 4 + (threadIdx.x >> 6);
    int lane = threadIdx.x & 63;
    if (node >= NITEMS) return;
    int j = istart[node], dg = ideg[node], end = j + dg;
    float a0 = 0.f, a1 = 0.f;
    for (; j + 1 < end; j += 2) {
        int s0 = csr[j], s1 = csr[j + 1];
        a0 += uemb[s0 * 64 + lane];
        a1 += uemb[s1 * 64 + lane];
    }
    if (j < end) a0 += uemb[csr[j] * 64 + lane];
    float dgf = (float)dg;
    float inv = 1.0f / fmaxf(dgf, 1.0f);
    float sw = 1.0f - dgf / (dgf + 1e-8f);
    float v = sw * iemb[node * 64 + lane] + (a0 + a1) * inv;
    ri1[node * 64 + lane] = __float2bfloat16(v);
}

// ---- batch rating means: ru1c[b]=mean(iemb[li]), ru2c[b]=mean(ri1[li]) ----
__global__ void k_batch_rat(const int* __restrict__ users, const float* __restrict__ iemb,
                            const bf16* __restrict__ ri1, const int* __restrict__ csr,
                            const int* __restrict__ ustart, const int* __restrict__ udeg,
                            float* __restrict__ ru1c, float* __restrict__ ru2c) {
    int b = blockIdx.x * 4 + (threadIdx.x >> 6);
    int lane = threadIdx.x & 63;
    if (b >= NBATCH) return;
    int u = users[b];
    int j = ustart[u], dg = udeg[u], end = j + dg;
    float a1 = 0.f, a2 = 0.f;
    for (; j < end; ++j) {
        int it = csr[j];
        a1 += iemb[it * 64 + lane];
        a2 += __bfloat162float(ri1[it * 64 + lane]);
    }
    float inv = 1.0f / fmaxf((float)dg, 1.0f);
    ru1c[b * 64 + lane] = a1 * inv;
    ru2c[b * 64 + lane] = a2 * inv;
}

// ---- soc1 = mean(uemb[social sources]); only where needed ----
__global__ void k_gather_soc(const float* __restrict__ uemb,
                             const int* __restrict__ csr, const int* __restrict__ sstart,
                             const int* __restrict__ sdeg,
                             const unsigned char* __restrict__ needed,
                             bf16* __restrict__ soc1) {
    int node = blockIdx.x * 4 + (threadIdx.x >> 6);
    int lane = threadIdx.x & 63;
    if (node >= NUSERS) return;
    if (!needed[node]) return;   // row never read -> skip
    int j = sstart[node], dg = sdeg[node], end = j + dg;
    float a0 = 0.f, a1 = 0.f;
    for (; j + 1 < end; j += 2) {
        int s0 = csr[j], s1 = csr[j + 1];
        a0 += uemb[s0 * 64 + lane];
        a1 += uemb[s1 * 64 + lane];
    }
    if (j < end) a0 += uemb[csr[j] * 64 + lane];
    float inv = 1.0f / fmaxf((float)dg, 1.0f);
    soc1[node * 64 + lane] = __float2bfloat16((a0 + a1) * inv);
}

// ---- fused batch social mean + epilogue; one wave per batch element ----
__global__ void k_final(const int* __restrict__ users, const int* __restrict__ items,
                        const float* __restrict__ uemb, const float* __restrict__ iemb,
                        const bf16* __restrict__ soc1, const int* __restrict__ csr,
                        const int* __restrict__ sstart, const int* __restrict__ sdeg,
                        const float* __restrict__ ru1c, const float* __restrict__ ru2c,
                        const int* __restrict__ udeg, float* __restrict__ out) {
    int b = blockIdx.x * 4 + (threadIdx.x >> 6);
    int d = threadIdx.x & 63;
    if (b >= NBATCH) return;
    int u = users[b], it = items[b];
    int j = sstart[u], dg = sdeg[u], end = j + dg;
    float a = 0.f;
    for (; j < end; ++j)
        a += __bfloat162float(soc1[csr[j] * 64 + d]);
    float s2 = a / fmaxf((float)dg, 1.0f);
    float ud = (float)udeg[u];
    float usw = 1.0f - ud / (ud + 1e-8f);       // f32: 1 if deg==0 else 0
    float ue = uemb[u * 64 + d];
    float s1 = __bfloat162float(soc1[u * 64 + d]);
    float r1 = usw * ue + ru1c[b * 64 + d];
    float r2 = usw * r1 + ru2c[b * 64 + d];
    float fu = ue + 0.5f * (s1 + r1) + 0.5f * (s2 + r2);
    float iv = iemb[it * 64 + d];
    out[NBATCH + b * 64 + d]               = fu;
    out[NBATCH + NBATCH * 64 + b * 64 + d] = iv;
    float p = fu * iv;
    #pragma unroll
    for (int o = 32; o > 0; o >>= 1) p += __shfl_down(p, o);
    if (d == 0) out[b] = 1.0f / (1.0f + __expf(-p));
}

extern "C" void kernel_launch(void* const* d_in, const int* in_sizes, int n_in,
                              void* d_out, int out_size, void* d_ws, size_t ws_size,
                              hipStream_t stream) {
    const float* uemb  = (const float*)d_in[0];
    const float* iemb  = (const float*)d_in[1];
    const int*   users = (const int*)d_in[2];
    const int*   items = (const int*)d_in[3];
    const int*   ssrc  = (const int*)d_in[4];
    const int*   sdst  = (const int*)d_in[5];
    const int*   lu    = (const int*)d_in[6];
    const int*   li    = (const int*)d_in[7];
    float* out = (float*)d_out;

    if (ws_size < (size_t)WS_FLOATS * 4) return;  // would show absmax==0.5 diagnostic

    int*           W      = (int*)d_ws;
    int*           gcnt   = W + OFF_GC;
    int*           gbase  = W + OFF_GB;
    int*           gcur   = W + OFF_GCUR;
    unsigned char* needed = (unsigned char*)(W + OFF_NEED);
    int*           slot   = W + OFF_SLOT;
    int*           ideg   = W + OFF_IDEG;
    int*           udeg   = W + OFF_UDEG;
    int*           sdeg   = W + OFF_SDEG;
    int*           istart = W + OFF_ISTART;
    int*           ustart = W + OFF_USTART;
    int*           sstart = W + OFF_SSTART;
    int*           partLI = W + OFF_PARTLI;
    int*           partLU = W + OFF_PARTLU;
    int*           partSD = W + OFF_PARTSD;
    int*           csrli  = W + OFF_CSRLI;
    int*           csrlu  = W + OFF_CSRLU;
    int*           csrsd  = W + OFF_CSRSD;
    bf16*          ri1    = (bf16*)(W + OFF_RI1);
    float*         ru1c   = (float*)(W + OFF_RU1C);
    float*         ru2c   = (float*)(W + OFF_RU2C);
    bf16*          soc1   = (bf16*)(W + OFF_SOC1);  // overlays part*/csrli

    hipMemsetAsync(d_ws, 0, (size_t)OFF_ZEND * 4, stream);   // gcnt + needed
    hipMemsetAsync(slot, 0xFF, (size_t)NUSERS * 4, stream);  // slot = -1

    const int B = 256;
    const int gE = (NEDGE + B - 1) / B;

    // CSR build (bucket-partitioned, no scattered global ops)
    k_slot<<<(NBATCH + B - 1) / B, B, 0, stream>>>(users, slot, needed);
    k_passA<<<gE, B, 0, stream>>>(lu, li, sdst, ssrc, slot, gcnt, needed);
    k_passB<<<1, B, 0, stream>>>(gcnt, gbase, gcur);
    k_passC<<<gE, B, 0, stream>>>(lu, li, sdst, ssrc, slot, gcur,
                                  partLI, partLU, partSD);
    k_passD<<<588, B, 0, stream>>>(gcnt, gbase, partLI, partLU, partSD,
                                   csrli, csrlu, csrsd, ideg, udeg, sdeg,
                                   istart, ustart, sstart);

    // rating branch
    k_gather_item<<<(NITEMS + 3) / 4, B, 0, stream>>>(iemb, uemb, csrli, istart, ideg, ri1);
    k_batch_rat<<<(NBATCH + 3) / 4, B, 0, stream>>>(users, iemb, ri1, csrlu, ustart,
                                                    udeg, ru1c, ru2c);
    // social branch (soc1 overlay only covers dead part*/csrli)
    k_gather_soc<<<(NUSERS + 3) / 4, B, 0, stream>>>(uemb, csrsd, sstart, sdeg, needed, soc1);

    // fused batch social mean + epilogue
    k_final<<<(NBATCH + 3) / 4, B, 0, stream>>>(users, items, uemb, iemb, soc1,
                                                csrsd, sstart, sdeg, ru1c, ru2c, udeg, out);
}

// Round 9
// 348.421 us; speedup vs baseline: 6.6489x; 1.3586x over previous
//
#include <hip/hip_runtime.h>
#include <hip/hip_bf16.h>

#define NUSERS 100000
#define NITEMS 50000
#define NEDGE  1000000
#define NBATCH 16384
#define CAP_LU 320000     // filtered like-edges of batch users; expected ~151K (2x margin)
#define EPB    2048       // edges per block in passA/passC (8 per thread)
#define NBLK_E ((NEDGE + EPB - 1) / EPB)   // 489

// ---- workspace layout, units of 4 bytes; total 8,964,456 units = 35.86 MB ----
#define OFF_GC     0                          // 3*256 bucket counts (memset 0)
#define OFF_GB     768                        // 3*256 bucket bases
#define OFF_GCUR   1536                       // 3*256 bucket cursors
#define OFF_NEED   2304                       // NUSERS bytes = 25000 units (memset 0)
#define OFF_ZEND   (OFF_NEED + NUSERS / 4)    // 27,304 end of memset-0 region
#define OFF_SLOT   OFF_ZEND                   // NUSERS int (memset 0xFF)
#define OFF_IDEG   (OFF_SLOT + NUSERS)
#define OFF_UDEG   (OFF_IDEG + NITEMS)
#define OFF_SDEG   (OFF_UDEG + NUSERS)
#define OFF_ISTART (OFF_SDEG + NUSERS)
#define OFF_USTART (OFF_ISTART + NITEMS)
#define OFF_SSTART (OFF_USTART + NUSERS)
#define OFF_PARTLI (OFF_SSTART + NUSERS)      // 627,304; NEDGE (dead after passD)
#define OFF_PARTLU (OFF_PARTLI + NEDGE)       // CAP_LU  (dead after passD)
#define OFF_PARTSD (OFF_PARTLU + CAP_LU)      // NEDGE   (dead after passD)
#define OFF_CSRLI  (OFF_PARTSD + NEDGE)       // NEDGE   (dead after gather_item)
#define OFF_CSRLU  (OFF_CSRLI + NEDGE)        // CAP_LU  (live till batch_rat)
#define OFF_RI1    (OFF_CSRLU + CAP_LU)       // NITEMS*32 bf16 (live till batch_rat)
#define OFF_CSRSD  (OFF_RI1 + NITEMS * 32)    // NEDGE (live till k_final)
#define OFF_RU1C   (OFF_CSRSD + NEDGE)        // NBATCH*64 f32
#define OFF_RU2C   (OFF_RU1C + NBATCH * 64)   // NBATCH*64 f32
#define WS_FLOATS  (OFF_RU2C + NBATCH * 64)   // 8,964,456
// soc1 (NUSERS*64 bf16 = 3.2M units) overlays partLI+partLU+partSD+head of csrli
// = [627,304 .. 3,827,304) < OFF_CSRLU (3,947,304). All dead before gather_soc.
#define OFF_SOC1   OFF_PARTLI

typedef __hip_bfloat16 bf16;

// ---- batch membership ----
__global__ void k_slot(const int* __restrict__ users, int* __restrict__ slot,
                       unsigned char* __restrict__ needed) {
    int b = blockIdx.x * blockDim.x + threadIdx.x;
    if (b < NBATCH) {
        int u = users[b];
        slot[u] = b;          // duplicate users: any winner fine (membership only)
        needed[u] = 1;
    }
}

// ---- pass A: per-block LDS bucket histograms (2048 edges/block) ----
__global__ void k_passA(const int* __restrict__ lu, const int* __restrict__ li,
                        const int* __restrict__ sd, const int* __restrict__ ss,
                        const int* __restrict__ slot, int* __restrict__ gcnt,
                        unsigned char* __restrict__ needed) {
    __shared__ int lc[768];
    int t = threadIdx.x;
    for (int k = t; k < 768; k += 256) lc[k] = 0;
    __syncthreads();
    int base = blockIdx.x * EPB;
    int end = base + EPB; if (end > NEDGE) end = NEDGE;
    for (int e = base + t; e < end; e += 256) {
        int item = li[e], a = lu[e], d = sd[e];
        atomicAdd(&lc[item >> 9], 1);                        // list0: by item
        if (slot[a] >= 0) atomicAdd(&lc[256 + (a >> 9)], 1); // list1: batch users
        atomicAdd(&lc[512 + (d >> 9)], 1);                   // list2: by dst user
        if (slot[d] >= 0) needed[ss[e]] = 1;                 // soc1 needed at source
    }
    __syncthreads();
    for (int k = t; k < 768; k += 256)
        if (lc[k]) atomicAdd(&gcnt[k], lc[k]);
}

// ---- pass B: one block; 3 exclusive scans of 256 bucket counts ----
__global__ void k_passB(const int* __restrict__ gcnt, int* __restrict__ gbase,
                        int* __restrict__ gcur) {
    __shared__ int s[256];
    int t = threadIdx.x;
    for (int j = 0; j < 3; ++j) {
        int v = gcnt[j * 256 + t];
        s[t] = v;
        __syncthreads();
        for (int o = 1; o < 256; o <<= 1) {
            int x = (t >= o) ? s[t - o] : 0;
            __syncthreads();
            s[t] += x;
            __syncthreads();
        }
        int ex = s[t] - v;
        gbase[j * 256 + t] = ex;
        gcur[j * 256 + t] = ex;
        __syncthreads();
    }
}

// ---- pass C: partition edges into per-bucket chunks (2048 edges/block =>
//      ~21-edge chunks for list0, ~10 for list2: coalesced chunk writes) ----
__global__ void k_passC(const int* __restrict__ lu, const int* __restrict__ li,
                        const int* __restrict__ sd, const int* __restrict__ ss,
                        const int* __restrict__ slot, int* __restrict__ gcur,
                        int* __restrict__ partLI, int* __restrict__ partLU,
                        int* __restrict__ partSD) {
    __shared__ int lc[768];   // local counts, then rank counters
    __shared__ int go[768];   // this block's global chunk offsets
    int t = threadIdx.x;
    for (int k = t; k < 768; k += 256) lc[k] = 0;
    __syncthreads();
    int base = blockIdx.x * EPB;
    int end = base + EPB; if (end > NEDGE) end = NEDGE;
    // phase 1: count
    for (int e = base + t; e < end; e += 256) {
        int item = li[e], a = lu[e], d = sd[e];
        atomicAdd(&lc[item >> 9], 1);
        if (slot[a] >= 0) atomicAdd(&lc[256 + (a >> 9)], 1);
        atomicAdd(&lc[512 + (d >> 9)], 1);
    }
    __syncthreads();
    // allocate chunks
    for (int k = t; k < 768; k += 256) {
        go[k] = lc[k] ? atomicAdd(&gcur[k], lc[k]) : 0;
        lc[k] = 0;
    }
    __syncthreads();
    // phase 2: rank-scatter into chunks (edge slice is L2-hot from phase 1)
    for (int e = base + t; e < end; e += 256) {
        int item = li[e], a = lu[e], d = sd[e], s_ = ss[e];
        int b0 = item >> 9;
        int r0 = atomicAdd(&lc[b0], 1);
        partLI[go[b0] + r0] = (a << 9) | (item & 511);
        if (slot[a] >= 0) {
            int b1 = 256 + (a >> 9);
            int r1 = atomicAdd(&lc[b1], 1);
            partLU[go[b1] + r1] = (item << 9) | (a & 511);
        }
        int b2 = 512 + (d >> 9);
        int r2 = atomicAdd(&lc[b2], 1);
        partSD[go[b2] + r2] = (s_ << 9) | (d & 511);
    }
}

// ---- pass D: one block per bucket; local count/scan -> deg/start (coalesced)
//      + rank-scatter CSR values into the bucket's compact window ----
__global__ void k_passD(const int* __restrict__ gcnt, const int* __restrict__ gbase,
                        const int* __restrict__ partLI, const int* __restrict__ partLU,
                        const int* __restrict__ partSD, int* __restrict__ csrli,
                        int* __restrict__ csrlu, int* __restrict__ csrsd,
                        int* __restrict__ ideg, int* __restrict__ udeg,
                        int* __restrict__ sdeg, int* __restrict__ istart,
                        int* __restrict__ ustart, int* __restrict__ sstart) {
    __shared__ int lcnt[512], lstart[512], sb[2][512];
    int t = threadIdx.x;
    int blk = blockIdx.x, list, b;
    const int* part; int* csr; int* deg; int* start; int n;
    if (blk < 196)      { list = 0; b = blk;       part = partLI; csr = csrli; deg = ideg; start = istart; n = NITEMS; }
    else if (blk < 392) { list = 1; b = blk - 196; part = partLU; csr = csrlu; deg = udeg; start = ustart; n = NUSERS; }
    else                { list = 2; b = blk - 392; part = partSD; csr = csrsd; deg = sdeg; start = sstart; n = NUSERS; }
    int base = gbase[list * 256 + b], cnt = gcnt[list * 256 + b];
    int node0 = b << 9;
    int M = n - node0; if (M > 512) M = 512; if (M < 0) M = 0;

    lcnt[t] = 0; lcnt[t + 256] = 0;
    __syncthreads();
    for (int i = t; i < cnt; i += 256) atomicAdd(&lcnt[part[base + i] & 511], 1);
    __syncthreads();
    sb[0][t] = lcnt[t]; sb[0][t + 256] = lcnt[t + 256];
    __syncthreads();
    int pp = 0;
    for (int o = 1; o < 512; o <<= 1) {
        int np = pp ^ 1;
        for (int k = t; k < 512; k += 256) {
            int v = sb[pp][k];
            if (k >= o) v += sb[pp][k - o];
            sb[np][k] = v;
        }
        __syncthreads();
        pp = np;
    }
    for (int k = t; k < 512; k += 256) {
        int ex = sb[pp][k] - lcnt[k];       // exclusive scan
        lstart[k] = ex;
        if (k < M) { deg[node0 + k] = lcnt[k]; start[node0 + k] = base + ex; }
    }
    __syncthreads();
    lcnt[t] = 0; lcnt[t + 256] = 0;
    __syncthreads();
    for (int i = t; i < cnt; i += 256) {
        int p = part[base + i];
        int nl = p & 511;
        int r = atomicAdd(&lcnt[nl], 1);
        csr[base + lstart[nl] + r] = p >> 9;  // window stays in one XCD's L2
    }
}

// ---- ri1 = i_sw*iemb + mean(uemb[liking users]); one wave per item ----
__global__ void k_gather_item(const float* __restrict__ iemb,
                              const float* __restrict__ uemb,
                              const int* __restrict__ csr, const int* __restrict__ istart,
                              const int* __restrict__ ideg, bf16* __restrict__ ri1) {
    int node = blockIdx.x * 4 + (threadIdx.x >> 6);
    int lane = threadIdx.x & 63;
    if (node >= NITEMS) return;
    int j = istart[node], dg = ideg[node], end = j + dg;
    float a0 = 0.f, a1 = 0.f;
    for (; j + 1 < end; j += 2) {
        int s0 = csr[j], s1 = csr[j + 1];
        a0 += uemb[s0 * 64 + lane];
        a1 += uemb[s1 * 64 + lane];
    }
    if (j < end) a0 += uemb[csr[j] * 64 + lane];
    float dgf = (float)dg;
    float inv = 1.0f / fmaxf(dgf, 1.0f);
    float sw = 1.0f - dgf / (dgf + 1e-8f);
    float v = sw * iemb[node * 64 + lane] + (a0 + a1) * inv;
    ri1[node * 64 + lane] = __float2bfloat16(v);
}

// ---- batch rating means: ru1c[b]=mean(iemb[li]), ru2c[b]=mean(ri1[li]) ----
__global__ void k_batch_rat(const int* __restrict__ users, const float* __restrict__ iemb,
                            const bf16* __restrict__ ri1, const int* __restrict__ csr,
                            const int* __restrict__ ustart, const int* __restrict__ udeg,
                            float* __restrict__ ru1c, float* __restrict__ ru2c) {
    int b = blockIdx.x * 4 + (threadIdx.x >> 6);
    int lane = threadIdx.x & 63;
    if (b >= NBATCH) return;
    int u = users[b];
    int j = ustart[u], dg = udeg[u], end = j + dg;
    float a1 = 0.f, a2 = 0.f;
    for (; j < end; ++j) {
        int it = csr[j];
        a1 += iemb[it * 64 + lane];
        a2 += __bfloat162float(ri1[it * 64 + lane]);
    }
    float inv = 1.0f / fmaxf((float)dg, 1.0f);
    ru1c[b * 64 + lane] = a1 * inv;
    ru2c[b * 64 + lane] = a2 * inv;
}

// ---- soc1 = mean(uemb[social sources]); only where needed ----
__global__ void k_gather_soc(const float* __restrict__ uemb,
                             const int* __restrict__ csr, const int* __restrict__ sstart,
                             const int* __restrict__ sdeg,
                             const unsigned char* __restrict__ needed,
                             bf16* __restrict__ soc1) {
    int node = blockIdx.x * 4 + (threadIdx.x >> 6);
    int lane = threadIdx.x & 63;
    if (node >= NUSERS) return;
    if (!needed[node]) return;   // row never read -> skip
    int j = sstart[node], dg = sdeg[node], end = j + dg;
    float a0 = 0.f, a1 = 0.f;
    for (; j + 1 < end; j += 2) {
        int s0 = csr[j], s1 = csr[j + 1];
        a0 += uemb[s0 * 64 + lane];
        a1 += uemb[s1 * 64 + lane];
    }
    if (j < end) a0 += uemb[csr[j] * 64 + lane];
    float inv = 1.0f / fmaxf((float)dg, 1.0f);
    soc1[node * 64 + lane] = __float2bfloat16((a0 + a1) * inv);
}

// ---- fused batch social mean + epilogue; one wave per batch element ----
__global__ void k_final(const int* __restrict__ users, const int* __restrict__ items,
                        const float* __restrict__ uemb, const float* __restrict__ iemb,
                        const bf16* __restrict__ soc1, const int* __restrict__ csr,
                        const int* __restrict__ sstart, const int* __restrict__ sdeg,
                        const float* __restrict__ ru1c, const float* __restrict__ ru2c,
                        const int* __restrict__ udeg, float* __restrict__ out) {
    int b = blockIdx.x * 4 + (threadIdx.x >> 6);
    int d = threadIdx.x & 63;
    if (b >= NBATCH) return;
    int u = users[b], it = items[b];
    int j = sstart[u], dg = sdeg[u], end = j + dg;
    float a = 0.f;
    for (; j < end; ++j)
        a += __bfloat162float(soc1[csr[j] * 64 + d]);
    float s2 = a / fmaxf((float)dg, 1.0f);
    float ud = (float)udeg[u];
    float usw = 1.0f - ud / (ud + 1e-8f);       // f32: 1 if deg==0 else 0
    float ue = uemb[u * 64 + d];
    float s1 = __bfloat162float(soc1[u * 64 + d]);
    float r1 = usw * ue + ru1c[b * 64 + d];
    float r2 = usw * r1 + ru2c[b * 64 + d];
    float fu = ue + 0.5f * (s1 + r1) + 0.5f * (s2 + r2);
    float iv = iemb[it * 64 + d];
    out[NBATCH + b * 64 + d]               = fu;
    out[NBATCH + NBATCH * 64 + b * 64 + d] = iv;
    float p = fu * iv;
    #pragma unroll
    for (int o = 32; o > 0; o >>= 1) p += __shfl_down(p, o);
    if (d == 0) out[b] = 1.0f / (1.0f + __expf(-p));
}

extern "C" void kernel_launch(void* const* d_in, const int* in_sizes, int n_in,
                              void* d_out, int out_size, void* d_ws, size_t ws_size,
                              hipStream_t stream) {
    const float* uemb  = (const float*)d_in[0];
    const float* iemb  = (const float*)d_in[1];
    const int*   users = (const int*)d_in[2];
    const int*   items = (const int*)d_in[3];
    const int*   ssrc  = (const int*)d_in[4];
    const int*   sdst  = (const int*)d_in[5];
    const int*   lu    = (const int*)d_in[6];
    const int*   li    = (const int*)d_in[7];
    float* out = (float*)d_out;

    if (ws_size < (size_t)WS_FLOATS * 4) return;  // would show absmax==0.5 diagnostic

    int*           W      = (int*)d_ws;
    int*           gcnt   = W + OFF_GC;
    int*           gbase  = W + OFF_GB;
    int*           gcur   = W + OFF_GCUR;
    unsigned char* needed = (unsigned char*)(W + OFF_NEED);
    int*           slot   = W + OFF_SLOT;
    int*           ideg   = W + OFF_IDEG;
    int*           udeg   = W + OFF_UDEG;
    int*           sdeg   = W + OFF_SDEG;
    int*           istart = W + OFF_ISTART;
    int*           ustart = W + OFF_USTART;
    int*           sstart = W + OFF_SSTART;
    int*           partLI = W + OFF_PARTLI;
    int*           partLU = W + OFF_PARTLU;
    int*           partSD = W + OFF_PARTSD;
    int*           csrli  = W + OFF_CSRLI;
    int*           csrlu  = W + OFF_CSRLU;
    int*           csrsd  = W + OFF_CSRSD;
    bf16*          ri1    = (bf16*)(W + OFF_RI1);
    float*         ru1c   = (float*)(W + OFF_RU1C);
    float*         ru2c   = (float*)(W + OFF_RU2C);
    bf16*          soc1   = (bf16*)(W + OFF_SOC1);  // overlays part*/csrli

    hipMemsetAsync(d_ws, 0, (size_t)OFF_ZEND * 4, stream);   // gcnt + needed
    hipMemsetAsync(slot, 0xFF, (size_t)NUSERS * 4, stream);  // slot = -1

    const int B = 256;

    // CSR build (bucket-partitioned, chunked writes)
    k_slot<<<(NBATCH + B - 1) / B, B, 0, stream>>>(users, slot, needed);
    k_passA<<<NBLK_E, B, 0, stream>>>(lu, li, sdst, ssrc, slot, gcnt, needed);
    k_passB<<<1, B, 0, stream>>>(gcnt, gbase, gcur);
    k_passC<<<NBLK_E, B, 0, stream>>>(lu, li, sdst, ssrc, slot, gcur,
                                      partLI, partLU, partSD);
    k_passD<<<588, B, 0, stream>>>(gcnt, gbase, partLI, partLU, partSD,
                                   csrli, csrlu, csrsd, ideg, udeg, sdeg,
                                   istart, ustart, sstart);

    // rating branch
    k_gather_item<<<(NITEMS + 3) / 4, B, 0, stream>>>(iemb, uemb, csrli, istart, ideg, ri1);
    k_batch_rat<<<(NBATCH + 3) / 4, B, 0, stream>>>(users, iemb, ri1, csrlu, ustart,
                                                    udeg, ru1c, ru2c);
    // social branch (soc1 overlay only covers dead part*/csrli)
    k_gather_soc<<<(NUSERS + 3) / 4, B, 0, stream>>>(uemb, csrsd, sstart, sdeg, needed, soc1);

    // fused batch social mean + epilogue
    k_final<<<(NBATCH + 3) / 4, B, 0, stream>>>(users, items, uemb, iemb, soc1,
                                                csrsd, sstart, sdeg, ru1c, ru2c, udeg, out);
}

// Round 11
// 324.218 us; speedup vs baseline: 7.1452x; 1.0747x over previous
//
#include <hip/hip_runtime.h>
#include <hip/hip_bf16.h>

#define NUSERS 100000
#define NITEMS 50000
#define NEDGE  1000000
#define NBATCH 16384
#define CAP_LU 320000     // filtered like-edges of batch users; expected ~164K (2x margin)
#define EPB    2048       // edges per block in passA/passC (8 per thread)
#define NBLK_E ((NEDGE + EPB - 1) / EPB)   // 489

// ---- workspace layout, units of 4 bytes; total 9,075,880 units = 36.3 MB ----
// Overlays:
//   uembh (bf16 uemb shadow, 3.2M units) = [627,304 .. 3,827,304): covers
//     partLI+partLU+partSD (dead after passD; k_cvt runs after passD) + 0.88M pad.
//   soc1  (bf16, 3.2M units) = [3,827,304 .. 7,027,304): covers csrli (dead after
//     gather_item) + csrlu + ri1 (dead after batch_rat) + 0.28M pad. gather_soc
//     runs after batch_rat. csrsd/ru1c/ru2c live beyond both overlays.
#define OFF_GC     0                          // 256*3 bucket counts (memset 0)
#define OFF_GB     768
#define OFF_GCUR   1536
#define OFF_NEED   2304                       // NUSERS bytes = 25000 units (memset 0)
#define OFF_ZEND   (OFF_NEED + NUSERS / 4)    // 27,304
#define OFF_SLOT   OFF_ZEND                   // NUSERS int (memset 0xFF)
#define OFF_IDEG   (OFF_SLOT + NUSERS)
#define OFF_UDEG   (OFF_IDEG + NITEMS)
#define OFF_SDEG   (OFF_UDEG + NUSERS)
#define OFF_ISTART (OFF_SDEG + NUSERS)
#define OFF_USTART (OFF_ISTART + NITEMS)
#define OFF_SSTART (OFF_USTART + NUSERS)
#define OFF_PARTLI (OFF_SSTART + NUSERS)      // 627,304
#define OFF_PARTLU (OFF_PARTLI + NEDGE)
#define OFF_PARTSD (OFF_PARTLU + CAP_LU)
#define OFF_UEMBH  OFF_PARTLI                 // NUSERS*32 units (bf16 shadow)
#define OFF_CSRLI  (OFF_UEMBH + NUSERS * 32)  // 3,827,304
#define OFF_CSRLU  (OFF_CSRLI + NEDGE)
#define OFF_RI1    (OFF_CSRLU + CAP_LU)       // NITEMS*32 units (bf16)
#define OFF_SOC1   OFF_CSRLI                  // NUSERS*32 units overlay
#define OFF_CSRSD  (OFF_SOC1 + NUSERS * 32)   // 7,027,304 (LIVE till k_final)
#define OFF_RU1C   (OFF_CSRSD + NEDGE)        // NBATCH*64 bf16 = 524,288 units
#define OFF_RU2C   (OFF_RU1C + NBATCH * 32)
#define WS_FLOATS  (OFF_RU2C + NBATCH * 32)   // 9,075,880

typedef unsigned short u16;

__device__ __forceinline__ float bf2f(u16 h) {
    union { unsigned u; float f; } c; c.u = ((unsigned)h) << 16; return c.f;
}
__device__ __forceinline__ u16 f2bf(float f) {
    union { float f; unsigned u; } c; c.f = f;
    unsigned r = c.u + 0x7fffu + ((c.u >> 16) & 1u);   // RNE
    return (u16)(r >> 16);
}

// ---- batch membership ----
__global__ void k_slot(const int* __restrict__ users, int* __restrict__ slot,
                       unsigned char* __restrict__ needed) {
    int b = blockIdx.x * blockDim.x + threadIdx.x;
    if (b < NBATCH) {
        int u = users[b];
        slot[u] = b;          // duplicate users: any winner fine (membership only)
        needed[u] = 1;
    }
}

// ---- pass A: per-block LDS bucket histograms (2048 edges/block) ----
__global__ void k_passA(const int* __restrict__ lu, const int* __restrict__ li,
                        const int* __restrict__ sd, const int* __restrict__ ss,
                        const int* __restrict__ slot, int* __restrict__ gcnt,
                        unsigned char* __restrict__ needed) {
    __shared__ int lc[768];
    int t = threadIdx.x;
    for (int k = t; k < 768; k += 256) lc[k] = 0;
    __syncthreads();
    int base = blockIdx.x * EPB;
    int end = base + EPB; if (end > NEDGE) end = NEDGE;
    for (int e = base + t; e < end; e += 256) {
        int item = li[e], a = lu[e], d = sd[e];
        atomicAdd(&lc[item >> 9], 1);                        // list0: by item
        if (slot[a] >= 0) atomicAdd(&lc[256 + (a >> 9)], 1); // list1: batch users
        atomicAdd(&lc[512 + (d >> 9)], 1);                   // list2: by dst user
        if (slot[d] >= 0) needed[ss[e]] = 1;                 // soc1 needed at source
    }
    __syncthreads();
    for (int k = t; k < 768; k += 256)
        if (lc[k]) atomicAdd(&gcnt[k], lc[k]);
}

// ---- pass B: one block; 3 exclusive scans of 256 bucket counts ----
__global__ void k_passB(const int* __restrict__ gcnt, int* __restrict__ gbase,
                        int* __restrict__ gcur) {
    __shared__ int s[256];
    int t = threadIdx.x;
    for (int j = 0; j < 3; ++j) {
        int v = gcnt[j * 256 + t];
        s[t] = v;
        __syncthreads();
        for (int o = 1; o < 256; o <<= 1) {
            int x = (t >= o) ? s[t - o] : 0;
            __syncthreads();
            s[t] += x;
            __syncthreads();
        }
        int ex = s[t] - v;
        gbase[j * 256 + t] = ex;
        gcur[j * 256 + t] = ex;
        __syncthreads();
    }
}

// ---- pass C: partition edges into per-bucket chunks ----
__global__ void k_passC(const int* __restrict__ lu, const int* __restrict__ li,
                        const int* __restrict__ sd, const int* __restrict__ ss,
                        const int* __restrict__ slot, int* __restrict__ gcur,
                        int* __restrict__ partLI, int* __restrict__ partLU,
                        int* __restrict__ partSD) {
    __shared__ int lc[768];   // local counts, then rank counters
    __shared__ int go[768];   // this block's global chunk offsets
    int t = threadIdx.x;
    for (int k = t; k < 768; k += 256) lc[k] = 0;
    __syncthreads();
    int base = blockIdx.x * EPB;
    int end = base + EPB; if (end > NEDGE) end = NEDGE;
    for (int e = base + t; e < end; e += 256) {
        int item = li[e], a = lu[e], d = sd[e];
        atomicAdd(&lc[item >> 9], 1);
        if (slot[a] >= 0) atomicAdd(&lc[256 + (a >> 9)], 1);
        atomicAdd(&lc[512 + (d >> 9)], 1);
    }
    __syncthreads();
    for (int k = t; k < 768; k += 256) {
        go[k] = lc[k] ? atomicAdd(&gcur[k], lc[k]) : 0;
        lc[k] = 0;
    }
    __syncthreads();
    for (int e = base + t; e < end; e += 256) {
        int item = li[e], a = lu[e], d = sd[e], s_ = ss[e];
        int b0 = item >> 9;
        int r0 = atomicAdd(&lc[b0], 1);
        partLI[go[b0] + r0] = (a << 9) | (item & 511);
        if (slot[a] >= 0) {
            int b1 = 256 + (a >> 9);
            int r1 = atomicAdd(&lc[b1], 1);
            partLU[go[b1] + r1] = (item << 9) | (a & 511);
        }
        int b2 = 512 + (d >> 9);
        int r2 = atomicAdd(&lc[b2], 1);
        partSD[go[b2] + r2] = (s_ << 9) | (d & 511);
    }
}

// ---- pass D: one block per bucket; count/scan -> deg/start + rank-scatter ----
__global__ void k_passD(const int* __restrict__ gcnt, const int* __restrict__ gbase,
                        const int* __restrict__ partLI, const int* __restrict__ partLU,
                        const int* __restrict__ partSD, int* __restrict__ csrli,
                        int* __restrict__ csrlu, int* __restrict__ csrsd,
                        int* __restrict__ ideg, int* __restrict__ udeg,
                        int* __restrict__ sdeg, int* __restrict__ istart,
                        int* __restrict__ ustart, int* __restrict__ sstart) {
    __shared__ int lcnt[512], lstart[512], sb[2][512];
    int t = threadIdx.x;
    int blk = blockIdx.x, list, b;
    const int* part; int* csr; int* deg; int* start; int n;
    if (blk < 196)      { list = 0; b = blk;       part = partLI; csr = csrli; deg = ideg; start = istart; n = NITEMS; }
    else if (blk < 392) { list = 1; b = blk - 196; part = partLU; csr = csrlu; deg = udeg; start = ustart; n = NUSERS; }
    else                { list = 2; b = blk - 392; part = partSD; csr = csrsd; deg = sdeg; start = sstart; n = NUSERS; }
    int base = gbase[list * 256 + b], cnt = gcnt[list * 256 + b];
    int node0 = b << 9;
    int M = n - node0; if (M > 512) M = 512; if (M < 0) M = 0;

    lcnt[t] = 0; lcnt[t + 256] = 0;
    __syncthreads();
    for (int i = t; i < cnt; i += 256) atomicAdd(&lcnt[part[base + i] & 511], 1);
    __syncthreads();
    sb[0][t] = lcnt[t]; sb[0][t + 256] = lcnt[t + 256];
    __syncthreads();
    int pp = 0;
    for (int o = 1; o < 512; o <<= 1) {
        int np = pp ^ 1;
        for (int k = t; k < 512; k += 256) {
            int v = sb[pp][k];
            if (k >= o) v += sb[pp][k - o];
            sb[np][k] = v;
        }
        __syncthreads();
        pp = np;
    }
    for (int k = t; k < 512; k += 256) {
        int ex = sb[pp][k] - lcnt[k];       // exclusive scan
        lstart[k] = ex;
        if (k < M) { deg[node0 + k] = lcnt[k]; start[node0 + k] = base + ex; }
    }
    __syncthreads();
    lcnt[t] = 0; lcnt[t + 256] = 0;
    __syncthreads();
    for (int i = t; i < cnt; i += 256) {
        int p = part[base + i];
        int nl = p & 511;
        int r = atomicAdd(&lcnt[nl], 1);
        csr[base + lstart[nl] + r] = p >> 9;  // window stays in one XCD's L2
    }
}

// ---- bf16 shadow of uemb (runs after passD; overlays dead part*) ----
__global__ void k_cvt(const float* __restrict__ src, u16* __restrict__ dst) {
    int t = blockIdx.x * 256 + threadIdx.x;
    if (t >= NUSERS * 16) return;                 // 16 float4 per row
    float4 v = ((const float4*)src)[t];
    ushort4 o;
    o.x = f2bf(v.x); o.y = f2bf(v.y); o.z = f2bf(v.z); o.w = f2bf(v.w);
    ((ushort4*)dst)[t] = o;
}

// ---- ri1 = i_sw*iemb + mean(uembh[liking users]); one wave per item ----
__global__ void k_gather_item(const float* __restrict__ iemb,
                              const u16* __restrict__ uh,
                              const int* __restrict__ csr, const int* __restrict__ istart,
                              const int* __restrict__ ideg, u16* __restrict__ ri1) {
    int node = blockIdx.x * 4 + (threadIdx.x >> 6);
    int lane = threadIdx.x & 63;
    if (node >= NITEMS) return;
    int j = istart[node], dg = ideg[node], end = j + dg;
    float a0 = 0.f, a1 = 0.f, a2 = 0.f, a3 = 0.f;
    for (; j + 3 < end; j += 4) {
        int s0 = csr[j], s1 = csr[j + 1], s2 = csr[j + 2], s3 = csr[j + 3];
        a0 += bf2f(uh[s0 * 64 + lane]);
        a1 += bf2f(uh[s1 * 64 + lane]);
        a2 += bf2f(uh[s2 * 64 + lane]);
        a3 += bf2f(uh[s3 * 64 + lane]);
    }
    for (; j < end; ++j) a0 += bf2f(uh[csr[j] * 64 + lane]);
    float dgf = (float)dg;
    float inv = 1.0f / fmaxf(dgf, 1.0f);
    float sw = 1.0f - dgf / (dgf + 1e-8f);
    float v = sw * iemb[node * 64 + lane] + ((a0 + a1) + (a2 + a3)) * inv;
    ri1[node * 64 + lane] = f2bf(v);
}

// ---- batch rating means: ru1c[b]=mean(iemb[li]), ru2c[b]=mean(ri1[li]) ----
__global__ void k_batch_rat(const int* __restrict__ users, const float* __restrict__ iemb,
                            const u16* __restrict__ ri1, const int* __restrict__ csr,
                            const int* __restrict__ ustart, const int* __restrict__ udeg,
                            u16* __restrict__ ru1c, u16* __restrict__ ru2c) {
    int b = blockIdx.x * 4 + (threadIdx.x >> 6);
    int lane = threadIdx.x & 63;
    if (b >= NBATCH) return;
    int u = users[b];
    int j = ustart[u], dg = udeg[u], end = j + dg;
    float a1 = 0.f, a2 = 0.f;
    for (; j < end; ++j) {
        int it = csr[j];
        a1 += iemb[it * 64 + lane];
        a2 += bf2f(ri1[it * 64 + lane]);
    }
    float inv = 1.0f / fmaxf((float)dg, 1.0f);
    ru1c[b * 64 + lane] = f2bf(a1 * inv);
    ru2c[b * 64 + lane] = f2bf(a2 * inv);
}

// ---- soc1 = mean(uembh[social sources]); only where needed ----
__global__ void k_gather_soc(const u16* __restrict__ uh,
                             const int* __restrict__ csr, const int* __restrict__ sstart,
                             const int* __restrict__ sdeg,
                             const unsigned char* __restrict__ needed,
                             u16* __restrict__ soc1) {
    int node = blockIdx.x * 4 + (threadIdx.x >> 6);
    int lane = threadIdx.x & 63;
    if (node >= NUSERS) return;
    if (!needed[node]) return;   // row never read -> skip
    int j = sstart[node], dg = sdeg[node], end = j + dg;
    float a0 = 0.f, a1 = 0.f, a2 = 0.f, a3 = 0.f;
    for (; j + 3 < end; j += 4) {
        int s0 = csr[j], s1 = csr[j + 1], s2 = csr[j + 2], s3 = csr[j + 3];
        a0 += bf2f(uh[s0 * 64 + lane]);
        a1 += bf2f(uh[s1 * 64 + lane]);
        a2 += bf2f(uh[s2 * 64 + lane]);
        a3 += bf2f(uh[s3 * 64 + lane]);
    }
    for (; j < end; ++j) a0 += bf2f(uh[csr[j] * 64 + lane]);
    float inv = 1.0f / fmaxf((float)dg, 1.0f);
    soc1[node * 64 + lane] = f2bf(((a0 + a1) + (a2 + a3)) * inv);
}

// ---- fused batch social mean + epilogue; one wave per batch element ----
__global__ void k_final(const int* __restrict__ users, const int* __restrict__ items,
                        const float* __restrict__ uemb, const float* __restrict__ iemb,
                        const u16* __restrict__ soc1, const int* __restrict__ csr,
                        const int* __restrict__ sstart, const int* __restrict__ sdeg,
                        const u16* __restrict__ ru1c, const u16* __restrict__ ru2c,
                        const int* __restrict__ udeg, float* __restrict__ out) {
    int b = blockIdx.x * 4 + (threadIdx.x >> 6);
    int d = threadIdx.x & 63;
    if (b >= NBATCH) return;
    int u = users[b], it = items[b];
    int j = sstart[u], dg = sdeg[u], end = j + dg;
    float a = 0.f;
    for (; j < end; ++j)
        a += bf2f(soc1[csr[j] * 64 + d]);
    float s2 = a / fmaxf((float)dg, 1.0f);
    float ud = (float)udeg[u];
    float usw = 1.0f - ud / (ud + 1e-8f);       // f32: 1 if deg==0 else 0
    float ue = uemb[u * 64 + d];
    float s1 = bf2f(soc1[u * 64 + d]);
    float r1 = usw * ue + bf2f(ru1c[b * 64 + d]);
    float r2 = usw * r1 + bf2f(ru2c[b * 64 + d]);
    float fu = ue + 0.5f * (s1 + r1) + 0.5f * (s2 + r2);
    float iv = iemb[it * 64 + d];
    out[NBATCH + b * 64 + d]               = fu;
    out[NBATCH + NBATCH * 64 + b * 64 + d] = iv;
    float p = fu * iv;
    #pragma unroll
    for (int o = 32; o > 0; o >>= 1) p += __shfl_down(p, o);
    if (d == 0) out[b] = 1.0f / (1.0f + __expf(-p));
}

extern "C" void kernel_launch(void* const* d_in, const int* in_sizes, int n_in,
                              void* d_out, int out_size, void* d_ws, size_t ws_size,
                              hipStream_t stream) {
    const float* uemb  = (const float*)d_in[0];
    const float* iemb  = (const float*)d_in[1];
    const int*   users = (const int*)d_in[2];
    const int*   items = (const int*)d_in[3];
    const int*   ssrc  = (const int*)d_in[4];
    const int*   sdst  = (const int*)d_in[5];
    const int*   lu    = (const int*)d_in[6];
    const int*   li    = (const int*)d_in[7];
    float* out = (float*)d_out;

    if (ws_size < (size_t)WS_FLOATS * 4) return;  // would show absmax==0.5 diagnostic

    int*           W      = (int*)d_ws;
    int*           gcnt   = W + OFF_GC;
    int*           gbase  = W + OFF_GB;
    int*           gcur   = W + OFF_GCUR;
    unsigned char* needed = (unsigned char*)(W + OFF_NEED);
    int*           slot   = W + OFF_SLOT;
    int*           ideg   = W + OFF_IDEG;
    int*           udeg   = W + OFF_UDEG;
    int*           sdeg   = W + OFF_SDEG;
    int*           istart = W + OFF_ISTART;
    int*           ustart = W + OFF_USTART;
    int*           sstart = W + OFF_SSTART;
    int*           partLI = W + OFF_PARTLI;
    int*           partLU = W + OFF_PARTLU;
    int*           partSD = W + OFF_PARTSD;
    u16*           uembh  = (u16*)(W + OFF_UEMBH);   // overlays part* (post-passD)
    int*           csrli  = W + OFF_CSRLI;
    int*           csrlu  = W + OFF_CSRLU;
    int*           csrsd  = W + OFF_CSRSD;
    u16*           ri1    = (u16*)(W + OFF_RI1);
    u16*           soc1   = (u16*)(W + OFF_SOC1);    // overlays csrli/csrlu/ri1
    u16*           ru1c   = (u16*)(W + OFF_RU1C);
    u16*           ru2c   = (u16*)(W + OFF_RU2C);

    hipMemsetAsync(d_ws, 0, (size_t)OFF_ZEND * 4, stream);   // gcnt + needed
    hipMemsetAsync(slot, 0xFF, (size_t)NUSERS * 4, stream);  // slot = -1

    const int B = 256;

    // CSR build (bucket-partitioned, chunked writes)
    k_slot<<<(NBATCH + B - 1) / B, B, 0, stream>>>(users, slot, needed);
    k_passA<<<NBLK_E, B, 0, stream>>>(lu, li, sdst, ssrc, slot, gcnt, needed);
    k_passB<<<1, B, 0, stream>>>(gcnt, gbase, gcur);
    k_passC<<<NBLK_E, B, 0, stream>>>(lu, li, sdst, ssrc, slot, gcur,
                                      partLI, partLU, partSD);
    k_passD<<<588, B, 0, stream>>>(gcnt, gbase, partLI, partLU, partSD,
                                   csrli, csrlu, csrsd, ideg, udeg, sdeg,
                                   istart, ustart, sstart);

    // bf16 shadow of uemb (part* now dead)
    k_cvt<<<(NUSERS * 16 + B - 1) / B, B, 0, stream>>>(uemb, uembh);

    // rating branch
    k_gather_item<<<(NITEMS + 3) / 4, B, 0, stream>>>(iemb, uembh, csrli, istart, ideg, ri1);
    k_batch_rat<<<(NBATCH + 3) / 4, B, 0, stream>>>(users, iemb, ri1, csrlu, ustart,
                                                    udeg, ru1c, ru2c);
    // social branch (soc1 overlay only covers dead csrli/csrlu/ri1)
    k_gather_soc<<<(NUSERS + 3) / 4, B, 0, stream>>>(uembh, csrsd, sstart, sdeg, needed, soc1);

    // fused batch social mean + epilogue
    k_final<<<(NBATCH + 3) / 4, B, 0, stream>>>(users, items, uemb, iemb, soc1,
                                                csrsd, sstart, sdeg, ru1c, ru2c, udeg, out);
}

// Round 12
// 310.522 us; speedup vs baseline: 7.4604x; 1.0441x over previous
//
#include <hip/hip_runtime.h>
#include <hip/hip_bf16.h>

#define NUSERS 100000
#define NITEMS 50000
#define NEDGE  1000000
#define NBATCH 16384
#define CAP_LU 320000     // filtered like-edges of batch users; expected ~164K (2x margin)
#define EPB    2048       // edges per block in passA/passC (8 per thread)
#define NBLK_E ((NEDGE + EPB - 1) / EPB)   // 489

// ---- workspace layout, units of 4 bytes; total 9,075,880 units = 36.3 MB ----
// Overlays:
//   uembh (bf16 uemb shadow, 3.2M units) = [627,304 .. 3,827,304): covers
//     partLI+partLU+partSD (dead after passD; k_cvt runs after passD) + 0.88M pad.
//   soc1  (bf16, 3.2M units) = [3,827,304 .. 7,027,304): covers csrli (dead after
//     gather_item) + csrlu + ri1 (dead after batch_rat) + 0.28M pad. gather_soc
//     runs after batch_rat. csrsd/ru1c/ru2c live beyond both overlays.
#define OFF_GC     0                          // 256*3 bucket counts (memset 0)
#define OFF_GB     768
#define OFF_GCUR   1536
#define OFF_NEED   2304                       // NUSERS bytes = 25000 units (memset 0)
#define OFF_ZEND   (OFF_NEED + NUSERS / 4)    // 27,304
#define OFF_SLOT   OFF_ZEND                   // NUSERS int (memset 0xFF)
#define OFF_IDEG   (OFF_SLOT + NUSERS)
#define OFF_UDEG   (OFF_IDEG + NITEMS)
#define OFF_SDEG   (OFF_UDEG + NUSERS)
#define OFF_ISTART (OFF_SDEG + NUSERS)
#define OFF_USTART (OFF_ISTART + NITEMS)
#define OFF_SSTART (OFF_USTART + NUSERS)
#define OFF_PARTLI (OFF_SSTART + NUSERS)      // 627,304
#define OFF_PARTLU (OFF_PARTLI + NEDGE)
#define OFF_PARTSD (OFF_PARTLU + CAP_LU)
#define OFF_UEMBH  OFF_PARTLI                 // NUSERS*32 units (bf16 shadow)
#define OFF_CSRLI  (OFF_UEMBH + NUSERS * 32)  // 3,827,304
#define OFF_CSRLU  (OFF_CSRLI + NEDGE)
#define OFF_RI1    (OFF_CSRLU + CAP_LU)       // NITEMS*32 units (bf16)
#define OFF_SOC1   OFF_CSRLI                  // NUSERS*32 units overlay
#define OFF_CSRSD  (OFF_SOC1 + NUSERS * 32)   // 7,027,304 (LIVE till k_final)
#define OFF_RU1C   (OFF_CSRSD + NEDGE)        // NBATCH*64 bf16 = 524,288 units
#define OFF_RU2C   (OFF_RU1C + NBATCH * 32)
#define WS_FLOATS  (OFF_RU2C + NBATCH * 32)   // 9,075,880

typedef unsigned short u16;

__device__ __forceinline__ float bf2f(u16 h) {
    union { unsigned u; float f; } c; c.u = ((unsigned)h) << 16; return c.f;
}
__device__ __forceinline__ u16 f2bf(float f) {
    union { float f; unsigned u; } c; c.f = f;
    unsigned r = c.u + 0x7fffu + ((c.u >> 16) & 1u);   // RNE
    return (u16)(r >> 16);
}

// ---- batch membership ----
__global__ void k_slot(const int* __restrict__ users, int* __restrict__ slot,
                       unsigned char* __restrict__ needed) {
    int b = blockIdx.x * blockDim.x + threadIdx.x;
    if (b < NBATCH) {
        int u = users[b];
        slot[u] = b;          // duplicate users: any winner fine (membership only)
        needed[u] = 1;
    }
}

// ---- pass A: per-block LDS bucket histograms (2048 edges/block) ----
__global__ void k_passA(const int* __restrict__ lu, const int* __restrict__ li,
                        const int* __restrict__ sd, const int* __restrict__ ss,
                        const int* __restrict__ slot, int* __restrict__ gcnt,
                        unsigned char* __restrict__ needed) {
    __shared__ int lc[768];
    int t = threadIdx.x;
    for (int k = t; k < 768; k += 256) lc[k] = 0;
    __syncthreads();
    int base = blockIdx.x * EPB;
    int end = base + EPB; if (end > NEDGE) end = NEDGE;
    for (int e = base + t; e < end; e += 256) {
        int item = li[e], a = lu[e], d = sd[e];
        atomicAdd(&lc[item >> 9], 1);                        // list0: by item
        if (slot[a] >= 0) atomicAdd(&lc[256 + (a >> 9)], 1); // list1: batch users
        atomicAdd(&lc[512 + (d >> 9)], 1);                   // list2: by dst user
        if (slot[d] >= 0) needed[ss[e]] = 1;                 // soc1 needed at source
    }
    __syncthreads();
    for (int k = t; k < 768; k += 256)
        if (lc[k]) atomicAdd(&gcnt[k], lc[k]);
}

// ---- pass B: one block; 3 exclusive scans of 256 bucket counts ----
__global__ void k_passB(const int* __restrict__ gcnt, int* __restrict__ gbase,
                        int* __restrict__ gcur) {
    __shared__ int s[256];
    int t = threadIdx.x;
    for (int j = 0; j < 3; ++j) {
        int v = gcnt[j * 256 + t];
        s[t] = v;
        __syncthreads();
        for (int o = 1; o < 256; o <<= 1) {
            int x = (t >= o) ? s[t - o] : 0;
            __syncthreads();
            s[t] += x;
            __syncthreads();
        }
        int ex = s[t] - v;
        gbase[j * 256 + t] = ex;
        gcur[j * 256 + t] = ex;
        __syncthreads();
    }
}

// ---- pass C: partition edges into per-bucket chunks; slot verdicts from
//      phase 1 cached in a per-thread bitmask (no scattered re-reads) ----
__global__ void k_passC(const int* __restrict__ lu, const int* __restrict__ li,
                        const int* __restrict__ sd, const int* __restrict__ ss,
                        const int* __restrict__ slot, int* __restrict__ gcur,
                        int* __restrict__ partLI, int* __restrict__ partLU,
                        int* __restrict__ partSD) {
    __shared__ int lc[768];   // local counts, then rank counters
    __shared__ int go[768];   // this block's global chunk offsets
    int t = threadIdx.x;
    for (int k = t; k < 768; k += 256) lc[k] = 0;
    __syncthreads();
    int base = blockIdx.x * EPB;
    int end = base + EPB; if (end > NEDGE) end = NEDGE;
    unsigned mask = 0;        // bit i: edge (base + i*256 + t) belongs to a batch user
    int i = 0;
    for (int e = base + t; e < end; e += 256, ++i) {
        int item = li[e], a = lu[e], d = sd[e];
        atomicAdd(&lc[item >> 9], 1);
        if (slot[a] >= 0) { atomicAdd(&lc[256 + (a >> 9)], 1); mask |= (1u << i); }
        atomicAdd(&lc[512 + (d >> 9)], 1);
    }
    __syncthreads();
    for (int k = t; k < 768; k += 256) {
        go[k] = lc[k] ? atomicAdd(&gcur[k], lc[k]) : 0;
        lc[k] = 0;
    }
    __syncthreads();
    i = 0;
    for (int e = base + t; e < end; e += 256, ++i) {
        int item = li[e], a = lu[e], d = sd[e], s_ = ss[e];
        int b0 = item >> 9;
        int r0 = atomicAdd(&lc[b0], 1);
        partLI[go[b0] + r0] = (a << 9) | (item & 511);
        if (mask & (1u << i)) {
            int b1 = 256 + (a >> 9);
            int r1 = atomicAdd(&lc[b1], 1);
            partLU[go[b1] + r1] = (item << 9) | (a & 511);
        }
        int b2 = 512 + (d >> 9);
        int r2 = atomicAdd(&lc[b2], 1);
        partSD[go[b2] + r2] = (s_ << 9) | (d & 511);
    }
}

// ---- pass D: one block per bucket; count/scan -> deg/start + rank-scatter ----
__global__ void k_passD(const int* __restrict__ gcnt, const int* __restrict__ gbase,
                        const int* __restrict__ partLI, const int* __restrict__ partLU,
                        const int* __restrict__ partSD, int* __restrict__ csrli,
                        int* __restrict__ csrlu, int* __restrict__ csrsd,
                        int* __restrict__ ideg, int* __restrict__ udeg,
                        int* __restrict__ sdeg, int* __restrict__ istart,
                        int* __restrict__ ustart, int* __restrict__ sstart) {
    __shared__ int lcnt[512], lstart[512], sb[2][512];
    int t = threadIdx.x;
    int blk = blockIdx.x, list, b;
    const int* part; int* csr; int* deg; int* start; int n;
    if (blk < 196)      { list = 0; b = blk;       part = partLI; csr = csrli; deg = ideg; start = istart; n = NITEMS; }
    else if (blk < 392) { list = 1; b = blk - 196; part = partLU; csr = csrlu; deg = udeg; start = ustart; n = NUSERS; }
    else                { list = 2; b = blk - 392; part = partSD; csr = csrsd; deg = sdeg; start = sstart; n = NUSERS; }
    int base = gbase[list * 256 + b], cnt = gcnt[list * 256 + b];
    int node0 = b << 9;
    int M = n - node0; if (M > 512) M = 512; if (M < 0) M = 0;

    lcnt[t] = 0; lcnt[t + 256] = 0;
    __syncthreads();
    for (int i = t; i < cnt; i += 256) atomicAdd(&lcnt[part[base + i] & 511], 1);
    __syncthreads();
    sb[0][t] = lcnt[t]; sb[0][t + 256] = lcnt[t + 256];
    __syncthreads();
    int pp = 0;
    for (int o = 1; o < 512; o <<= 1) {
        int np = pp ^ 1;
        for (int k = t; k < 512; k += 256) {
            int v = sb[pp][k];
            if (k >= o) v += sb[pp][k - o];
            sb[np][k] = v;
        }
        __syncthreads();
        pp = np;
    }
    for (int k = t; k < 512; k += 256) {
        int ex = sb[pp][k] - lcnt[k];       // exclusive scan
        lstart[k] = ex;
        if (k < M) { deg[node0 + k] = lcnt[k]; start[node0 + k] = base + ex; }
    }
    __syncthreads();
    lcnt[t] = 0; lcnt[t + 256] = 0;
    __syncthreads();
    for (int i = t; i < cnt; i += 256) {
        int p = part[base + i];
        int nl = p & 511;
        int r = atomicAdd(&lcnt[nl], 1);
        csr[base + lstart[nl] + r] = p >> 9;  // window stays in one XCD's L2
    }
}

// ---- bf16 shadow of uemb (runs after passD; overlays dead part*) ----
__global__ void k_cvt(const float* __restrict__ src, u16* __restrict__ dst) {
    int t = blockIdx.x * 256 + threadIdx.x;
    if (t >= NUSERS * 16) return;                 // 16 float4 per row
    float4 v = ((const float4*)src)[t];
    ushort4 o;
    o.x = f2bf(v.x); o.y = f2bf(v.y); o.z = f2bf(v.z); o.w = f2bf(v.w);
    ((ushort4*)dst)[t] = o;
}

// ---- ri1 = i_sw*iemb + mean(uembh[liking users]); one wave per item ----
__global__ void k_gather_item(const float* __restrict__ iemb,
                              const u16* __restrict__ uh,
                              const int* __restrict__ csr, const int* __restrict__ istart,
                              const int* __restrict__ ideg, u16* __restrict__ ri1) {
    int node = blockIdx.x * 4 + (threadIdx.x >> 6);
    int lane = threadIdx.x & 63;
    if (node >= NITEMS) return;
    int j = istart[node], dg = ideg[node], end = j + dg;
    float a0 = 0.f, a1 = 0.f, a2 = 0.f, a3 = 0.f;
    for (; j + 7 < end; j += 8) {                 // 8 outstanding row loads
        int s0 = csr[j],     s1 = csr[j + 1], s2 = csr[j + 2], s3 = csr[j + 3];
        int s4 = csr[j + 4], s5 = csr[j + 5], s6 = csr[j + 6], s7 = csr[j + 7];
        float f0 = bf2f(uh[s0 * 64 + lane]), f1 = bf2f(uh[s1 * 64 + lane]);
        float f2 = bf2f(uh[s2 * 64 + lane]), f3 = bf2f(uh[s3 * 64 + lane]);
        float f4 = bf2f(uh[s4 * 64 + lane]), f5 = bf2f(uh[s5 * 64 + lane]);
        float f6 = bf2f(uh[s6 * 64 + lane]), f7 = bf2f(uh[s7 * 64 + lane]);
        a0 += f0 + f4; a1 += f1 + f5; a2 += f2 + f6; a3 += f3 + f7;
    }
    for (; j < end; ++j) a0 += bf2f(uh[csr[j] * 64 + lane]);
    float dgf = (float)dg;
    float inv = 1.0f / fmaxf(dgf, 1.0f);
    float sw = 1.0f - dgf / (dgf + 1e-8f);
    float v = sw * iemb[node * 64 + lane] + ((a0 + a1) + (a2 + a3)) * inv;
    ri1[node * 64 + lane] = f2bf(v);
}

// ---- batch rating means: ru1c[b]=mean(iemb[li]), ru2c[b]=mean(ri1[li]) ----
__global__ void k_batch_rat(const int* __restrict__ users, const float* __restrict__ iemb,
                            const u16* __restrict__ ri1, const int* __restrict__ csr,
                            const int* __restrict__ ustart, const int* __restrict__ udeg,
                            u16* __restrict__ ru1c, u16* __restrict__ ru2c) {
    int b = blockIdx.x * 4 + (threadIdx.x >> 6);
    int lane = threadIdx.x & 63;
    if (b >= NBATCH) return;
    int u = users[b];
    int j = ustart[u], dg = udeg[u], end = j + dg;
    float a1 = 0.f, a2 = 0.f, b1 = 0.f, b2 = 0.f;
    for (; j + 1 < end; j += 2) {
        int i0 = csr[j], i1 = csr[j + 1];
        a1 += iemb[i0 * 64 + lane];
        b1 += iemb[i1 * 64 + lane];
        a2 += bf2f(ri1[i0 * 64 + lane]);
        b2 += bf2f(ri1[i1 * 64 + lane]);
    }
    if (j < end) {
        int i0 = csr[j];
        a1 += iemb[i0 * 64 + lane];
        a2 += bf2f(ri1[i0 * 64 + lane]);
    }
    float inv = 1.0f / fmaxf((float)dg, 1.0f);
    ru1c[b * 64 + lane] = f2bf((a1 + b1) * inv);
    ru2c[b * 64 + lane] = f2bf((a2 + b2) * inv);
}

// ---- soc1 = mean(uembh[social sources]); only where needed ----
__global__ void k_gather_soc(const u16* __restrict__ uh,
                             const int* __restrict__ csr, const int* __restrict__ sstart,
                             const int* __restrict__ sdeg,
                             const unsigned char* __restrict__ needed,
                             u16* __restrict__ soc1) {
    int node = blockIdx.x * 4 + (threadIdx.x >> 6);
    int lane = threadIdx.x & 63;
    if (node >= NUSERS) return;
    if (!needed[node]) return;   // row never read -> skip
    int j = sstart[node], dg = sdeg[node], end = j + dg;
    float a0 = 0.f, a1 = 0.f, a2 = 0.f, a3 = 0.f;
    for (; j + 7 < end; j += 8) {                 // 8 outstanding row loads
        int s0 = csr[j],     s1 = csr[j + 1], s2 = csr[j + 2], s3 = csr[j + 3];
        int s4 = csr[j + 4], s5 = csr[j + 5], s6 = csr[j + 6], s7 = csr[j + 7];
        float f0 = bf2f(uh[s0 * 64 + lane]), f1 = bf2f(uh[s1 * 64 + lane]);
        float f2 = bf2f(uh[s2 * 64 + lane]), f3 = bf2f(uh[s3 * 64 + lane]);
        float f4 = bf2f(uh[s4 * 64 + lane]), f5 = bf2f(uh[s5 * 64 + lane]);
        float f6 = bf2f(uh[s6 * 64 + lane]), f7 = bf2f(uh[s7 * 64 + lane]);
        a0 += f0 + f4; a1 += f1 + f5; a2 += f2 + f6; a3 += f3 + f7;
    }
    for (; j < end; ++j) a0 += bf2f(uh[csr[j] * 64 + lane]);
    float inv = 1.0f / fmaxf((float)dg, 1.0f);
    soc1[node * 64 + lane] = f2bf(((a0 + a1) + (a2 + a3)) * inv);
}

// ---- fused batch social mean + epilogue; one wave per batch element ----
__global__ void k_final(const int* __restrict__ users, const int* __restrict__ items,
                        const float* __restrict__ uemb, const float* __restrict__ iemb,
                        const u16* __restrict__ soc1, const int* __restrict__ csr,
                        const int* __restrict__ sstart, const int* __restrict__ sdeg,
                        const u16* __restrict__ ru1c, const u16* __restrict__ ru2c,
                        const int* __restrict__ udeg, float* __restrict__ out) {
    int b = blockIdx.x * 4 + (threadIdx.x >> 6);
    int d = threadIdx.x & 63;
    if (b >= NBATCH) return;
    int u = users[b], it = items[b];
    int j = sstart[u], dg = sdeg[u], end = j + dg;
    float a = 0.f, a2_ = 0.f;
    for (; j + 1 < end; j += 2) {
        int c0 = csr[j], c1 = csr[j + 1];
        a   += bf2f(soc1[c0 * 64 + d]);
        a2_ += bf2f(soc1[c1 * 64 + d]);
    }
    if (j < end) a += bf2f(soc1[csr[j] * 64 + d]);
    float s2 = (a + a2_) / fmaxf((float)dg, 1.0f);
    float ud = (float)udeg[u];
    float usw = 1.0f - ud / (ud + 1e-8f);       // f32: 1 if deg==0 else 0
    float ue = uemb[u * 64 + d];
    float s1 = bf2f(soc1[u * 64 + d]);
    float r1 = usw * ue + bf2f(ru1c[b * 64 + d]);
    float r2 = usw * r1 + bf2f(ru2c[b * 64 + d]);
    float fu = ue + 0.5f * (s1 + r1) + 0.5f * (s2 + r2);
    float iv = iemb[it * 64 + d];
    out[NBATCH + b * 64 + d]               = fu;
    out[NBATCH + NBATCH * 64 + b * 64 + d] = iv;
    float p = fu * iv;
    #pragma unroll
    for (int o = 32; o > 0; o >>= 1) p += __shfl_down(p, o);
    if (d == 0) out[b] = 1.0f / (1.0f + __expf(-p));
}

extern "C" void kernel_launch(void* const* d_in, const int* in_sizes, int n_in,
                              void* d_out, int out_size, void* d_ws, size_t ws_size,
                              hipStream_t stream) {
    const float* uemb  = (const float*)d_in[0];
    const float* iemb  = (const float*)d_in[1];
    const int*   users = (const int*)d_in[2];
    const int*   items = (const int*)d_in[3];
    const int*   ssrc  = (const int*)d_in[4];
    const int*   sdst  = (const int*)d_in[5];
    const int*   lu    = (const int*)d_in[6];
    const int*   li    = (const int*)d_in[7];
    float* out = (float*)d_out;

    if (ws_size < (size_t)WS_FLOATS * 4) return;  // would show absmax==0.5 diagnostic

    int*           W      = (int*)d_ws;
    int*           gcnt   = W + OFF_GC;
    int*           gbase  = W + OFF_GB;
    int*           gcur   = W + OFF_GCUR;
    unsigned char* needed = (unsigned char*)(W + OFF_NEED);
    int*           slot   = W + OFF_SLOT;
    int*           ideg   = W + OFF_IDEG;
    int*           udeg   = W + OFF_UDEG;
    int*           sdeg   = W + OFF_SDEG;
    int*           istart = W + OFF_ISTART;
    int*           ustart = W + OFF_USTART;
    int*           sstart = W + OFF_SSTART;
    int*           partLI = W + OFF_PARTLI;
    int*           partLU = W + OFF_PARTLU;
    int*           partSD = W + OFF_PARTSD;
    u16*           uembh  = (u16*)(W + OFF_UEMBH);   // overlays part* (post-passD)
    int*           csrli  = W + OFF_CSRLI;
    int*           csrlu  = W + OFF_CSRLU;
    int*           csrsd  = W + OFF_CSRSD;
    u16*           ri1    = (u16*)(W + OFF_RI1);
    u16*           soc1   = (u16*)(W + OFF_SOC1);    // overlays csrli/csrlu/ri1
    u16*           ru1c   = (u16*)(W + OFF_RU1C);
    u16*           ru2c   = (u16*)(W + OFF_RU2C);

    hipMemsetAsync(d_ws, 0, (size_t)OFF_ZEND * 4, stream);   // gcnt + needed
    hipMemsetAsync(slot, 0xFF, (size_t)NUSERS * 4, stream);  // slot = -1

    const int B = 256;

    // CSR build (bucket-partitioned, chunked writes)
    k_slot<<<(NBATCH + B - 1) / B, B, 0, stream>>>(users, slot, needed);
    k_passA<<<NBLK_E, B, 0, stream>>>(lu, li, sdst, ssrc, slot, gcnt, needed);
    k_passB<<<1, B, 0, stream>>>(gcnt, gbase, gcur);
    k_passC<<<NBLK_E, B, 0, stream>>>(lu, li, sdst, ssrc, slot, gcur,
                                      partLI, partLU, partSD);
    k_passD<<<588, B, 0, stream>>>(gcnt, gbase, partLI, partLU, partSD,
                                   csrli, csrlu, csrsd, ideg, udeg, sdeg,
                                   istart, ustart, sstart);

    // bf16 shadow of uemb (part* now dead)
    k_cvt<<<(NUSERS * 16 + B - 1) / B, B, 0, stream>>>(uemb, uembh);

    // rating branch
    k_gather_item<<<(NITEMS + 3) / 4, B, 0, stream>>>(iemb, uembh, csrli, istart, ideg, ri1);
    k_batch_rat<<<(NBATCH + 3) / 4, B, 0, stream>>>(users, iemb, ri1, csrlu, ustart,
                                                    udeg, ru1c, ru2c);
    // social branch (soc1 overlay only covers dead csrli/csrlu/ri1)
    k_gather_soc<<<(NUSERS + 3) / 4, B, 0, stream>>>(uembh, csrsd, sstart, sdeg, needed, soc1);

    // fused batch social mean + epilogue
    k_final<<<(NBATCH + 3) / 4, B, 0, stream>>>(users, items, uemb, iemb, soc1,
                                                csrsd, sstart, sdeg, ru1c, ru2c, udeg, out);
}

// Round 13
// 307.145 us; speedup vs baseline: 7.5424x; 1.0110x over previous
//
#include <hip/hip_runtime.h>
#include <hip/hip_bf16.h>

#define NUSERS 100000
#define NITEMS 50000
#define NEDGE  1000000
#define NBATCH 16384
#define CAP_LU 320000     // filtered like-edges of batch users; expected ~164K (2x margin)
#define EPB    2048       // edges per block in passA/passC (8 per thread)
#define NBLK_E ((NEDGE + EPB - 1) / EPB)   // 489
#define NBW    3125       // NUSERS/32 bitmask words

// ---- workspace layout, units of 4 bytes; total 8,979,016 units = 35.9 MB ----
// Overlays:
//   uembh (bf16 uemb shadow, 3.2M units) = [530,440 .. 3,730,440): covers
//     partLI+partLU+partSD (dead after passD; k_cvt runs after passD) + pad.
//   soc1  (bf16, 3.2M units) = [3,730,440 .. 6,930,440): covers csrli (dead after
//     gather_item) + csrlu + ri1 (dead after batch_rat) + pad. gather_soc runs
//     after batch_rat. csrsd/ru1c/ru2c live beyond both overlays.
#define OFF_GC     0                          // 256*3 bucket counts (memset 0)
#define OFF_GB     768
#define OFF_GCUR   1536
#define OFF_BITS   2304                       // 3136 u32 batch-membership bitmask
#define OFF_NEED   (OFF_BITS + 3136)          // NUSERS bytes = 25000 units
#define OFF_ZEND   (OFF_NEED + NUSERS / 4)    // 30,440 end of memset-0 region
#define OFF_IDEG   OFF_ZEND
#define OFF_UDEG   (OFF_IDEG + NITEMS)
#define OFF_SDEG   (OFF_UDEG + NUSERS)
#define OFF_ISTART (OFF_SDEG + NUSERS)
#define OFF_USTART (OFF_ISTART + NITEMS)
#define OFF_SSTART (OFF_USTART + NUSERS)
#define OFF_PARTLI (OFF_SSTART + NUSERS)      // 530,440
#define OFF_PARTLU (OFF_PARTLI + NEDGE)
#define OFF_PARTSD (OFF_PARTLU + CAP_LU)
#define OFF_UEMBH  OFF_PARTLI                 // NUSERS*32 units (bf16 shadow)
#define OFF_CSRLI  (OFF_UEMBH + NUSERS * 32)  // 3,730,440
#define OFF_CSRLU  (OFF_CSRLI + NEDGE)
#define OFF_RI1    (OFF_CSRLU + CAP_LU)       // NITEMS*32 units (bf16)
#define OFF_SOC1   OFF_CSRLI                  // NUSERS*32 units overlay
#define OFF_CSRSD  (OFF_SOC1 + NUSERS * 32)   // 6,930,440 (LIVE till k_final)
#define OFF_RU1C   (OFF_CSRSD + NEDGE)        // NBATCH*64 bf16 = 524,288 units
#define OFF_RU2C   (OFF_RU1C + NBATCH * 32)
#define WS_FLOATS  (OFF_RU2C + NBATCH * 32)   // 8,979,016

typedef unsigned short u16;

__device__ __forceinline__ float bf2f(u16 h) {
    union { unsigned u; float f; } c; c.u = ((unsigned)h) << 16; return c.f;
}
__device__ __forceinline__ u16 f2bf(float f) {
    union { float f; unsigned u; } c; c.f = f;
    unsigned r = c.u + 0x7fffu + ((c.u >> 16) & 1u);   // RNE
    return (u16)(r >> 16);
}

// ---- batch membership: bitmask + needed flags ----
__global__ void k_slot(const int* __restrict__ users, unsigned* __restrict__ bits,
                       unsigned char* __restrict__ needed) {
    int b = blockIdx.x * blockDim.x + threadIdx.x;
    if (b < NBATCH) {
        int u = users[b];
        atomicOr(&bits[u >> 5], 1u << (u & 31));
        needed[u] = 1;
    }
}

// ---- pass A: per-block LDS bucket histograms; membership via LDS bitmask ----
__global__ void k_passA(const int* __restrict__ lu, const int* __restrict__ li,
                        const int* __restrict__ sd, const int* __restrict__ ss,
                        const unsigned* __restrict__ bits, int* __restrict__ gcnt,
                        unsigned char* __restrict__ needed) {
    __shared__ int lc[768];
    __shared__ unsigned sbits[NBW];
    int t = threadIdx.x;
    for (int k = t; k < 768; k += 256) lc[k] = 0;
    for (int k = t; k < NBW; k += 256) sbits[k] = bits[k];
    __syncthreads();
    int base = blockIdx.x * EPB;
    int end = base + EPB; if (end > NEDGE) end = NEDGE;
    for (int e = base + t; e < end; e += 256) {
        int item = li[e], a = lu[e], d = sd[e];
        atomicAdd(&lc[item >> 9], 1);                        // list0: by item
        if ((sbits[a >> 5] >> (a & 31)) & 1)                 // list1: batch users
            atomicAdd(&lc[256 + (a >> 9)], 1);
        atomicAdd(&lc[512 + (d >> 9)], 1);                   // list2: by dst user
        if ((sbits[d >> 5] >> (d & 31)) & 1)                 // soc1 needed at source
            needed[ss[e]] = 1;
    }
    __syncthreads();
    for (int k = t; k < 768; k += 256)
        if (lc[k]) atomicAdd(&gcnt[k], lc[k]);
}

// ---- pass B: one block; 3 exclusive scans of 256 bucket counts ----
__global__ void k_passB(const int* __restrict__ gcnt, int* __restrict__ gbase,
                        int* __restrict__ gcur) {
    __shared__ int s[256];
    int t = threadIdx.x;
    for (int j = 0; j < 3; ++j) {
        int v = gcnt[j * 256 + t];
        s[t] = v;
        __syncthreads();
        for (int o = 1; o < 256; o <<= 1) {
            int x = (t >= o) ? s[t - o] : 0;
            __syncthreads();
            s[t] += x;
            __syncthreads();
        }
        int ex = s[t] - v;
        gbase[j * 256 + t] = ex;
        gcur[j * 256 + t] = ex;
        __syncthreads();
    }
}

// ---- pass C: partition edges into per-bucket chunks; membership via LDS
//      bitmask in phase 1, cached in a register mask for phase 2 ----
__global__ void k_passC(const int* __restrict__ lu, const int* __restrict__ li,
                        const int* __restrict__ sd, const int* __restrict__ ss,
                        const unsigned* __restrict__ bits, int* __restrict__ gcur,
                        int* __restrict__ partLI, int* __restrict__ partLU,
                        int* __restrict__ partSD) {
    __shared__ int lc[768];   // local counts, then rank counters
    __shared__ int go[768];   // this block's global chunk offsets
    __shared__ unsigned sbits[NBW];
    int t = threadIdx.x;
    for (int k = t; k < 768; k += 256) lc[k] = 0;
    for (int k = t; k < NBW; k += 256) sbits[k] = bits[k];
    __syncthreads();
    int base = blockIdx.x * EPB;
    int end = base + EPB; if (end > NEDGE) end = NEDGE;
    unsigned mask = 0;        // bit i: edge (base + i*256 + t) belongs to a batch user
    int i = 0;
    for (int e = base + t; e < end; e += 256, ++i) {
        int item = li[e], a = lu[e], d = sd[e];
        atomicAdd(&lc[item >> 9], 1);
        if ((sbits[a >> 5] >> (a & 31)) & 1) {
            atomicAdd(&lc[256 + (a >> 9)], 1);
            mask |= (1u << i);
        }
        atomicAdd(&lc[512 + (d >> 9)], 1);
    }
    __syncthreads();
    for (int k = t; k < 768; k += 256) {
        go[k] = lc[k] ? atomicAdd(&gcur[k], lc[k]) : 0;
        lc[k] = 0;
    }
    __syncthreads();
    i = 0;
    for (int e = base + t; e < end; e += 256, ++i) {
        int item = li[e], a = lu[e], d = sd[e], s_ = ss[e];
        int b0 = item >> 9;
        int r0 = atomicAdd(&lc[b0], 1);
        partLI[go[b0] + r0] = (a << 9) | (item & 511);
        if (mask & (1u << i)) {
            int b1 = 256 + (a >> 9);
            int r1 = atomicAdd(&lc[b1], 1);
            partLU[go[b1] + r1] = (item << 9) | (a & 511);
        }
        int b2 = 512 + (d >> 9);
        int r2 = atomicAdd(&lc[b2], 1);
        partSD[go[b2] + r2] = (s_ << 9) | (d & 511);
    }
}

// ---- pass D: one block per bucket; count/scan -> deg/start + rank-scatter ----
__global__ void k_passD(const int* __restrict__ gcnt, const int* __restrict__ gbase,
                        const int* __restrict__ partLI, const int* __restrict__ partLU,
                        const int* __restrict__ partSD, int* __restrict__ csrli,
                        int* __restrict__ csrlu, int* __restrict__ csrsd,
                        int* __restrict__ ideg, int* __restrict__ udeg,
                        int* __restrict__ sdeg, int* __restrict__ istart,
                        int* __restrict__ ustart, int* __restrict__ sstart) {
    __shared__ int lcnt[512], lstart[512], sb[2][512];
    int t = threadIdx.x;
    int blk = blockIdx.x, list, b;
    const int* part; int* csr; int* deg; int* start; int n;
    if (blk < 196)      { list = 0; b = blk;       part = partLI; csr = csrli; deg = ideg; start = istart; n = NITEMS; }
    else if (blk < 392) { list = 1; b = blk - 196; part = partLU; csr = csrlu; deg = udeg; start = ustart; n = NUSERS; }
    else                { list = 2; b = blk - 392; part = partSD; csr = csrsd; deg = sdeg; start = sstart; n = NUSERS; }
    int base = gbase[list * 256 + b], cnt = gcnt[list * 256 + b];
    int node0 = b << 9;
    int M = n - node0; if (M > 512) M = 512; if (M < 0) M = 0;

    lcnt[t] = 0; lcnt[t + 256] = 0;
    __syncthreads();
    for (int i = t; i < cnt; i += 256) atomicAdd(&lcnt[part[base + i] & 511], 1);
    __syncthreads();
    sb[0][t] = lcnt[t]; sb[0][t + 256] = lcnt[t + 256];
    __syncthreads();
    int pp = 0;
    for (int o = 1; o < 512; o <<= 1) {
        int np = pp ^ 1;
        for (int k = t; k < 512; k += 256) {
            int v = sb[pp][k];
            if (k >= o) v += sb[pp][k - o];
            sb[np][k] = v;
        }
        __syncthreads();
        pp = np;
    }
    for (int k = t; k < 512; k += 256) {
        int ex = sb[pp][k] - lcnt[k];       // exclusive scan
        lstart[k] = ex;
        if (k < M) { deg[node0 + k] = lcnt[k]; start[node0 + k] = base + ex; }
    }
    __syncthreads();
    lcnt[t] = 0; lcnt[t + 256] = 0;
    __syncthreads();
    for (int i = t; i < cnt; i += 256) {
        int p = part[base + i];
        int nl = p & 511;
        int r = atomicAdd(&lcnt[nl], 1);
        csr[base + lstart[nl] + r] = p >> 9;  // window stays in one XCD's L2
    }
}

// ---- bf16 shadow of uemb (runs after passD; overlays dead part*) ----
__global__ void k_cvt(const float* __restrict__ src, u16* __restrict__ dst) {
    int t = blockIdx.x * 256 + threadIdx.x;
    if (t >= NUSERS * 16) return;                 // 16 float4 per row
    float4 v = ((const float4*)src)[t];
    ushort4 o;
    o.x = f2bf(v.x); o.y = f2bf(v.y); o.z = f2bf(v.z); o.w = f2bf(v.w);
    ((ushort4*)dst)[t] = o;
}

// ---- ri1 = i_sw*iemb + mean(uembh[liking users]); one wave per item ----
__global__ void k_gather_item(const float* __restrict__ iemb,
                              const u16* __restrict__ uh,
                              const int* __restrict__ csr, const int* __restrict__ istart,
                              const int* __restrict__ ideg, u16* __restrict__ ri1) {
    int node = blockIdx.x * 4 + (threadIdx.x >> 6);
    int lane = threadIdx.x & 63;
    if (node >= NITEMS) return;
    int j = istart[node], dg = ideg[node], end = j + dg;
    float a0 = 0.f, a1 = 0.f, a2 = 0.f, a3 = 0.f;
    for (; j + 7 < end; j += 8) {                 // 8 outstanding row loads
        int s0 = csr[j],     s1 = csr[j + 1], s2 = csr[j + 2], s3 = csr[j + 3];
        int s4 = csr[j + 4], s5 = csr[j + 5], s6 = csr[j + 6], s7 = csr[j + 7];
        float f0 = bf2f(uh[s0 * 64 + lane]), f1 = bf2f(uh[s1 * 64 + lane]);
        float f2 = bf2f(uh[s2 * 64 + lane]), f3 = bf2f(uh[s3 * 64 + lane]);
        float f4 = bf2f(uh[s4 * 64 + lane]), f5 = bf2f(uh[s5 * 64 + lane]);
        float f6 = bf2f(uh[s6 * 64 + lane]), f7 = bf2f(uh[s7 * 64 + lane]);
        a0 += f0 + f4; a1 += f1 + f5; a2 += f2 + f6; a3 += f3 + f7;
    }
    for (; j < end; ++j) a0 += bf2f(uh[csr[j] * 64 + lane]);
    float dgf = (float)dg;
    float inv = 1.0f / fmaxf(dgf, 1.0f);
    float sw = 1.0f - dgf / (dgf + 1e-8f);
    float v = sw * iemb[node * 64 + lane] + ((a0 + a1) + (a2 + a3)) * inv;
    ri1[node * 64 + lane] = f2bf(v);
}

// ---- batch rating means: ru1c[b]=mean(iemb[li]), ru2c[b]=mean(ri1[li]) ----
__global__ void k_batch_rat(const int* __restrict__ users, const float* __restrict__ iemb,
                            const u16* __restrict__ ri1, const int* __restrict__ csr,
                            const int* __restrict__ ustart, const int* __restrict__ udeg,
                            u16* __restrict__ ru1c, u16* __restrict__ ru2c) {
    int b = blockIdx.x * 4 + (threadIdx.x >> 6);
    int lane = threadIdx.x & 63;
    if (b >= NBATCH) return;
    int u = users[b];
    int j = ustart[u], dg = udeg[u], end = j + dg;
    float a1 = 0.f, a2 = 0.f, b1 = 0.f, b2 = 0.f;
    for (; j + 1 < end; j += 2) {
        int i0 = csr[j], i1 = csr[j + 1];
        a1 += iemb[i0 * 64 + lane];
        b1 += iemb[i1 * 64 + lane];
        a2 += bf2f(ri1[i0 * 64 + lane]);
        b2 += bf2f(ri1[i1 * 64 + lane]);
    }
    if (j < end) {
        int i0 = csr[j];
        a1 += iemb[i0 * 64 + lane];
        a2 += bf2f(ri1[i0 * 64 + lane]);
    }
    float inv = 1.0f / fmaxf((float)dg, 1.0f);
    ru1c[b * 64 + lane] = f2bf((a1 + b1) * inv);
    ru2c[b * 64 + lane] = f2bf((a2 + b2) * inv);
}

// ---- soc1 = mean(uembh[social sources]); only where needed ----
__global__ void k_gather_soc(const u16* __restrict__ uh,
                             const int* __restrict__ csr, const int* __restrict__ sstart,
                             const int* __restrict__ sdeg,
                             const unsigned char* __restrict__ needed,
                             u16* __restrict__ soc1) {
    int node = blockIdx.x * 4 + (threadIdx.x >> 6);
    int lane = threadIdx.x & 63;
    if (node >= NUSERS) return;
    if (!needed[node]) return;   // row never read -> skip
    int j = sstart[node], dg = sdeg[node], end = j + dg;
    float a0 = 0.f, a1 = 0.f, a2 = 0.f, a3 = 0.f;
    for (; j + 7 < end; j += 8) {                 // 8 outstanding row loads
        int s0 = csr[j],     s1 = csr[j + 1], s2 = csr[j + 2], s3 = csr[j + 3];
        int s4 = csr[j + 4], s5 = csr[j + 5], s6 = csr[j + 6], s7 = csr[j + 7];
        float f0 = bf2f(uh[s0 * 64 + lane]), f1 = bf2f(uh[s1 * 64 + lane]);
        float f2 = bf2f(uh[s2 * 64 + lane]), f3 = bf2f(uh[s3 * 64 + lane]);
        float f4 = bf2f(uh[s4 * 64 + lane]), f5 = bf2f(uh[s5 * 64 + lane]);
        float f6 = bf2f(uh[s6 * 64 + lane]), f7 = bf2f(uh[s7 * 64 + lane]);
        a0 += f0 + f4; a1 += f1 + f5; a2 += f2 + f6; a3 += f3 + f7;
    }
    for (; j < end; ++j) a0 += bf2f(uh[csr[j] * 64 + lane]);
    float inv = 1.0f / fmaxf((float)dg, 1.0f);
    soc1[node * 64 + lane] = f2bf(((a0 + a1) + (a2 + a3)) * inv);
}

// ---- fused batch social mean + epilogue; one wave per batch element ----
__global__ void k_final(const int* __restrict__ users, const int* __restrict__ items,
                        const float* __restrict__ uemb, const float* __restrict__ iemb,
                        const u16* __restrict__ soc1, const int* __restrict__ csr,
                        const int* __restrict__ sstart, const int* __restrict__ sdeg,
                        const u16* __restrict__ ru1c, const u16* __restrict__ ru2c,
                        const int* __restrict__ udeg, float* __restrict__ out) {
    int b = blockIdx.x * 4 + (threadIdx.x >> 6);
    int d = threadIdx.x & 63;
    if (b >= NBATCH) return;
    int u = users[b], it = items[b];
    int j = sstart[u], dg = sdeg[u], end = j + dg;
    float a = 0.f, a2_ = 0.f;
    for (; j + 1 < end; j += 2) {
        int c0 = csr[j], c1 = csr[j + 1];
        a   += bf2f(soc1[c0 * 64 + d]);
        a2_ += bf2f(soc1[c1 * 64 + d]);
    }
    if (j < end) a += bf2f(soc1[csr[j] * 64 + d]);
    float s2 = (a + a2_) / fmaxf((float)dg, 1.0f);
    float ud = (float)udeg[u];
    float usw = 1.0f - ud / (ud + 1e-8f);       // f32: 1 if deg==0 else 0
    float ue = uemb[u * 64 + d];
    float s1 = bf2f(soc1[u * 64 + d]);
    float r1 = usw * ue + bf2f(ru1c[b * 64 + d]);
    float r2 = usw * r1 + bf2f(ru2c[b * 64 + d]);
    float fu = ue + 0.5f * (s1 + r1) + 0.5f * (s2 + r2);
    float iv = iemb[it * 64 + d];
    out[NBATCH + b * 64 + d]               = fu;
    out[NBATCH + NBATCH * 64 + b * 64 + d] = iv;
    float p = fu * iv;
    #pragma unroll
    for (int o = 32; o > 0; o >>= 1) p += __shfl_down(p, o);
    if (d == 0) out[b] = 1.0f / (1.0f + __expf(-p));
}

extern "C" void kernel_launch(void* const* d_in, const int* in_sizes, int n_in,
                              void* d_out, int out_size, void* d_ws, size_t ws_size,
                              hipStream_t stream) {
    const float* uemb  = (const float*)d_in[0];
    const float* iemb  = (const float*)d_in[1];
    const int*   users = (const int*)d_in[2];
    const int*   items = (const int*)d_in[3];
    const int*   ssrc  = (const int*)d_in[4];
    const int*   sdst  = (const int*)d_in[5];
    const int*   lu    = (const int*)d_in[6];
    const int*   li    = (const int*)d_in[7];
    float* out = (float*)d_out;

    if (ws_size < (size_t)WS_FLOATS * 4) return;  // would show absmax==0.5 diagnostic

    int*           W      = (int*)d_ws;
    int*           gcnt   = W + OFF_GC;
    int*           gbase  = W + OFF_GB;
    int*           gcur   = W + OFF_GCUR;
    unsigned*      bits   = (unsigned*)(W + OFF_BITS);
    unsigned char* needed = (unsigned char*)(W + OFF_NEED);
    int*           ideg   = W + OFF_IDEG;
    int*           udeg   = W + OFF_UDEG;
    int*           sdeg   = W + OFF_SDEG;
    int*           istart = W + OFF_ISTART;
    int*           ustart = W + OFF_USTART;
    int*           sstart = W + OFF_SSTART;
    int*           partLI = W + OFF_PARTLI;
    int*           partLU = W + OFF_PARTLU;
    int*           partSD = W + OFF_PARTSD;
    u16*           uembh  = (u16*)(W + OFF_UEMBH);   // overlays part* (post-passD)
    int*           csrli  = W + OFF_CSRLI;
    int*           csrlu  = W + OFF_CSRLU;
    int*           csrsd  = W + OFF_CSRSD;
    u16*           ri1    = (u16*)(W + OFF_RI1);
    u16*           soc1   = (u16*)(W + OFF_SOC1);    // overlays csrli/csrlu/ri1
    u16*           ru1c   = (u16*)(W + OFF_RU1C);
    u16*           ru2c   = (u16*)(W + OFF_RU2C);

    hipMemsetAsync(d_ws, 0, (size_t)OFF_ZEND * 4, stream);   // gcnt + bits + needed

    const int B = 256;

    // CSR build (bucket-partitioned, chunked writes, LDS-bitmask membership)
    k_slot<<<(NBATCH + B - 1) / B, B, 0, stream>>>(users, bits, needed);
    k_passA<<<NBLK_E, B, 0, stream>>>(lu, li, sdst, ssrc, bits, gcnt, needed);
    k_passB<<<1, B, 0, stream>>>(gcnt, gbase, gcur);
    k_passC<<<NBLK_E, B, 0, stream>>>(lu, li, sdst, ssrc, bits, gcur,
                                      partLI, partLU, partSD);
    k_passD<<<588, B, 0, stream>>>(gcnt, gbase, partLI, partLU, partSD,
                                   csrli, csrlu, csrsd, ideg, udeg, sdeg,
                                   istart, ustart, sstart);

    // bf16 shadow of uemb (part* now dead)
    k_cvt<<<(NUSERS * 16 + B - 1) / B, B, 0, stream>>>(uemb, uembh);

    // rating branch
    k_gather_item<<<(NITEMS + 3) / 4, B, 0, stream>>>(iemb, uembh, csrli, istart, ideg, ri1);
    k_batch_rat<<<(NBATCH + 3) / 4, B, 0, stream>>>(users, iemb, ri1, csrlu, ustart,
                                                    udeg, ru1c, ru2c);
    // social branch (soc1 overlay only covers dead csrli/csrlu/ri1)
    k_gather_soc<<<(NUSERS + 3) / 4, B, 0, stream>>>(uembh, csrsd, sstart, sdeg, needed, soc1);

    // fused batch social mean + epilogue
    k_final<<<(NBATCH + 3) / 4, B, 0, stream>>>(users, items, uemb, iemb, soc1,
                                                csrsd, sstart, sdeg, ru1c, ru2c, udeg, out);
}

// Round 14
// 289.989 us; speedup vs baseline: 7.9886x; 1.0592x over previous
//
#include <hip/hip_runtime.h>
#include <hip/hip_bf16.h>

#define NUSERS 100000
#define NITEMS 50000
#define NEDGE  1000000
#define NBATCH 16384
#define CAP_LU 320000     // filtered like-edges of batch users; expected ~164K (2x margin)
#define EPB    2048       // edges per block in passA/passC (8 per thread)
#define NBLK_E ((NEDGE + EPB - 1) / EPB)   // 489
#define NBW    3125       // NUSERS/32 bitmask words

// ---- workspace layout, units of 4 bytes; total 8,979,016 units = 35.9 MB ----
// Overlays:
//   uembh (bf16 uemb shadow, 3.2M units) = [530,440 .. 3,730,440): covers
//     partLI+partLU+partSD (dead after passD; k_cvt runs after passD) + pad.
//   soc1  (bf16, 3.2M units) = [3,730,440 .. 6,930,440): covers csrli (dead after
//     gather_item) + csrlu + ri1 (dead after batch_rat) + pad. gather_soc runs
//     after batch_rat. csrsd/ru1c/ru2c live beyond both overlays.
#define OFF_GC     0                          // 256*3 bucket counts (memset 0)
#define OFF_GB     768
#define OFF_GCUR   1536
#define OFF_BITS   2304                       // 3136 u32 batch-membership bitmask
#define OFF_NEED   (OFF_BITS + 3136)          // NUSERS bytes = 25000 units
#define OFF_ZEND   (OFF_NEED + NUSERS / 4)    // 30,440 end of memset-0 region
#define OFF_IDEG   OFF_ZEND
#define OFF_UDEG   (OFF_IDEG + NITEMS)
#define OFF_SDEG   (OFF_UDEG + NUSERS)
#define OFF_ISTART (OFF_SDEG + NUSERS)
#define OFF_USTART (OFF_ISTART + NITEMS)
#define OFF_SSTART (OFF_USTART + NUSERS)
#define OFF_PARTLI (OFF_SSTART + NUSERS)      // 530,440
#define OFF_PARTLU (OFF_PARTLI + NEDGE)
#define OFF_PARTSD (OFF_PARTLU + CAP_LU)
#define OFF_UEMBH  OFF_PARTLI                 // NUSERS*32 units (bf16 shadow)
#define OFF_CSRLI  (OFF_UEMBH + NUSERS * 32)  // 3,730,440
#define OFF_CSRLU  (OFF_CSRLI + NEDGE)
#define OFF_RI1    (OFF_CSRLU + CAP_LU)       // NITEMS*32 units (bf16)
#define OFF_SOC1   OFF_CSRLI                  // NUSERS*32 units overlay
#define OFF_CSRSD  (OFF_SOC1 + NUSERS * 32)   // 6,930,440 (LIVE till k_final)
#define OFF_RU1C   (OFF_CSRSD + NEDGE)        // NBATCH*64 bf16 = 524,288 units
#define OFF_RU2C   (OFF_RU1C + NBATCH * 32)
#define WS_FLOATS  (OFF_RU2C + NBATCH * 32)   // 8,979,016

typedef unsigned short u16;

__device__ __forceinline__ float bf2f(u16 h) {
    union { unsigned u; float f; } c; c.u = ((unsigned)h) << 16; return c.f;
}
__device__ __forceinline__ u16 f2bf(float f) {
    union { float f; unsigned u; } c; c.f = f;
    unsigned r = c.u + 0x7fffu + ((c.u >> 16) & 1u);   // RNE
    return (u16)(r >> 16);
}
__device__ __forceinline__ void acc2(unsigned w, float& a0, float& a1) {
    a0 += bf2f((u16)(w & 0xffff));
    a1 += bf2f((u16)(w >> 16));
}

// ---- batch membership: bitmask + needed flags ----
__global__ void k_slot(const int* __restrict__ users, unsigned* __restrict__ bits,
                       unsigned char* __restrict__ needed) {
    int b = blockIdx.x * blockDim.x + threadIdx.x;
    if (b < NBATCH) {
        int u = users[b];
        atomicOr(&bits[u >> 5], 1u << (u & 31));
        needed[u] = 1;
    }
}

// ---- pass A: per-block LDS bucket histograms; membership via LDS bitmask ----
__global__ void k_passA(const int* __restrict__ lu, const int* __restrict__ li,
                        const int* __restrict__ sd, const int* __restrict__ ss,
                        const unsigned* __restrict__ bits, int* __restrict__ gcnt,
                        unsigned char* __restrict__ needed) {
    __shared__ int lc[768];
    __shared__ unsigned sbits[NBW];
    int t = threadIdx.x;
    for (int k = t; k < 768; k += 256) lc[k] = 0;
    for (int k = t; k < NBW; k += 256) sbits[k] = bits[k];
    __syncthreads();
    int base = blockIdx.x * EPB;
    int end = base + EPB; if (end > NEDGE) end = NEDGE;
    for (int e = base + t; e < end; e += 256) {
        int item = li[e], a = lu[e], d = sd[e];
        atomicAdd(&lc[item >> 9], 1);                        // list0: by item
        if ((sbits[a >> 5] >> (a & 31)) & 1)                 // list1: batch users
            atomicAdd(&lc[256 + (a >> 9)], 1);
        atomicAdd(&lc[512 + (d >> 9)], 1);                   // list2: by dst user
        if ((sbits[d >> 5] >> (d & 31)) & 1)                 // soc1 needed at source
            needed[ss[e]] = 1;
    }
    __syncthreads();
    for (int k = t; k < 768; k += 256)
        if (lc[k]) atomicAdd(&gcnt[k], lc[k]);
}

// ---- pass B: one block; 3 exclusive scans of 256 bucket counts ----
__global__ void k_passB(const int* __restrict__ gcnt, int* __restrict__ gbase,
                        int* __restrict__ gcur) {
    __shared__ int s[256];
    int t = threadIdx.x;
    for (int j = 0; j < 3; ++j) {
        int v = gcnt[j * 256 + t];
        s[t] = v;
        __syncthreads();
        for (int o = 1; o < 256; o <<= 1) {
            int x = (t >= o) ? s[t - o] : 0;
            __syncthreads();
            s[t] += x;
            __syncthreads();
        }
        int ex = s[t] - v;
        gbase[j * 256 + t] = ex;
        gcur[j * 256 + t] = ex;
        __syncthreads();
    }
}

// ---- pass C: partition edges into per-bucket chunks; membership via LDS
//      bitmask in phase 1, cached in a register mask for phase 2 ----
__global__ void k_passC(const int* __restrict__ lu, const int* __restrict__ li,
                        const int* __restrict__ sd, const int* __restrict__ ss,
                        const unsigned* __restrict__ bits, int* __restrict__ gcur,
                        int* __restrict__ partLI, int* __restrict__ partLU,
                        int* __restrict__ partSD) {
    __shared__ int lc[768];   // local counts, then rank counters
    __shared__ int go[768];   // this block's global chunk offsets
    __shared__ unsigned sbits[NBW];
    int t = threadIdx.x;
    for (int k = t; k < 768; k += 256) lc[k] = 0;
    for (int k = t; k < NBW; k += 256) sbits[k] = bits[k];
    __syncthreads();
    int base = blockIdx.x * EPB;
    int end = base + EPB; if (end > NEDGE) end = NEDGE;
    unsigned mask = 0;        // bit i: edge (base + i*256 + t) belongs to a batch user
    int i = 0;
    for (int e = base + t; e < end; e += 256, ++i) {
        int item = li[e], a = lu[e], d = sd[e];
        atomicAdd(&lc[item >> 9], 1);
        if ((sbits[a >> 5] >> (a & 31)) & 1) {
            atomicAdd(&lc[256 + (a >> 9)], 1);
            mask |= (1u << i);
        }
        atomicAdd(&lc[512 + (d >> 9)], 1);
    }
    __syncthreads();
    for (int k = t; k < 768; k += 256) {
        go[k] = lc[k] ? atomicAdd(&gcur[k], lc[k]) : 0;
        lc[k] = 0;
    }
    __syncthreads();
    i = 0;
    for (int e = base + t; e < end; e += 256, ++i) {
        int item = li[e], a = lu[e], d = sd[e], s_ = ss[e];
        int b0 = item >> 9;
        int r0 = atomicAdd(&lc[b0], 1);
        partLI[go[b0] + r0] = (a << 9) | (item & 511);
        if (mask & (1u << i)) {
            int b1 = 256 + (a >> 9);
            int r1 = atomicAdd(&lc[b1], 1);
            partLU[go[b1] + r1] = (item << 9) | (a & 511);
        }
        int b2 = 512 + (d >> 9);
        int r2 = atomicAdd(&lc[b2], 1);
        partSD[go[b2] + r2] = (s_ << 9) | (d & 511);
    }
}

// ---- pass D: one block per bucket; count/scan -> deg/start + rank-scatter ----
__global__ void k_passD(const int* __restrict__ gcnt, const int* __restrict__ gbase,
                        const int* __restrict__ partLI, const int* __restrict__ partLU,
                        const int* __restrict__ partSD, int* __restrict__ csrli,
                        int* __restrict__ csrlu, int* __restrict__ csrsd,
                        int* __restrict__ ideg, int* __restrict__ udeg,
                        int* __restrict__ sdeg, int* __restrict__ istart,
                        int* __restrict__ ustart, int* __restrict__ sstart) {
    __shared__ int lcnt[512], lstart[512], sb[2][512];
    int t = threadIdx.x;
    int blk = blockIdx.x, list, b;
    const int* part; int* csr; int* deg; int* start; int n;
    if (blk < 196)      { list = 0; b = blk;       part = partLI; csr = csrli; deg = ideg; start = istart; n = NITEMS; }
    else if (blk < 392) { list = 1; b = blk - 196; part = partLU; csr = csrlu; deg = udeg; start = ustart; n = NUSERS; }
    else                { list = 2; b = blk - 392; part = partSD; csr = csrsd; deg = sdeg; start = sstart; n = NUSERS; }
    int base = gbase[list * 256 + b], cnt = gcnt[list * 256 + b];
    int node0 = b << 9;
    int M = n - node0; if (M > 512) M = 512; if (M < 0) M = 0;

    lcnt[t] = 0; lcnt[t + 256] = 0;
    __syncthreads();
    for (int i = t; i < cnt; i += 256) atomicAdd(&lcnt[part[base + i] & 511], 1);
    __syncthreads();
    sb[0][t] = lcnt[t]; sb[0][t + 256] = lcnt[t + 256];
    __syncthreads();
    int pp = 0;
    for (int o = 1; o < 512; o <<= 1) {
        int np = pp ^ 1;
        for (int k = t; k < 512; k += 256) {
            int v = sb[pp][k];
            if (k >= o) v += sb[pp][k - o];
            sb[np][k] = v;
        }
        __syncthreads();
        pp = np;
    }
    for (int k = t; k < 512; k += 256) {
        int ex = sb[pp][k] - lcnt[k];       // exclusive scan
        lstart[k] = ex;
        if (k < M) { deg[node0 + k] = lcnt[k]; start[node0 + k] = base + ex; }
    }
    __syncthreads();
    lcnt[t] = 0; lcnt[t + 256] = 0;
    __syncthreads();
    for (int i = t; i < cnt; i += 256) {
        int p = part[base + i];
        int nl = p & 511;
        int r = atomicAdd(&lcnt[nl], 1);
        csr[base + lstart[nl] + r] = p >> 9;  // window stays in one XCD's L2
    }
}

// ---- bf16 shadow of uemb (runs after passD; overlays dead part*) ----
__global__ void k_cvt(const float* __restrict__ src, u16* __restrict__ dst) {
    int t = blockIdx.x * 256 + threadIdx.x;
    if (t >= NUSERS * 16) return;                 // 16 float4 per row
    float4 v = ((const float4*)src)[t];
    ushort4 o;
    o.x = f2bf(v.x); o.y = f2bf(v.y); o.z = f2bf(v.z); o.w = f2bf(v.w);
    ((ushort4*)dst)[t] = o;
}

// ---- ri1 = i_sw*iemb + mean(uembh[liking users]); one wave per item.
//      Pair-packed: half=lane>>5 picks csr entry parity, lane handles dims
//      2l,2l+1 as one dword -> each load instruction covers TWO source rows. ----
__global__ void k_gather_item(const float* __restrict__ iemb,
                              const unsigned* __restrict__ uh32,
                              const int* __restrict__ csr, const int* __restrict__ istart,
                              const int* __restrict__ ideg, unsigned* __restrict__ ri1) {
    int node = blockIdx.x * 4 + (threadIdx.x >> 6);
    int lane = threadIdx.x & 63;
    if (node >= NITEMS) return;
    int half = lane >> 5, l = lane & 31;
    int j = istart[node], dg = ideg[node], end = j + dg;
    float a0 = 0.f, b0 = 0.f, a1 = 0.f, b1 = 0.f, a2 = 0.f, b2 = 0.f, a3 = 0.f, b3 = 0.f;
    for (; j + 7 < end; j += 8) {                 // 4 insts = 8 rows in flight
        unsigned w0 = uh32[csr[j     + half] * 32 + l];
        unsigned w1 = uh32[csr[j + 2 + half] * 32 + l];
        unsigned w2 = uh32[csr[j + 4 + half] * 32 + l];
        unsigned w3 = uh32[csr[j + 6 + half] * 32 + l];
        acc2(w0, a0, b0); acc2(w1, a1, b1); acc2(w2, a2, b2); acc2(w3, a3, b3);
    }
    for (; j < end; j += 2) {                     // predicated tail
        int idx = j + half;
        if (idx < end) { unsigned w = uh32[csr[idx] * 32 + l]; acc2(w, a0, b0); }
    }
    float s0 = (a0 + a1) + (a2 + a3);
    float s1 = (b0 + b1) + (b2 + b3);
    s0 += __shfl_xor(s0, 32);                     // combine entry parities
    s1 += __shfl_xor(s1, 32);
    if (half == 0) {
        float dgf = (float)dg;
        float inv = 1.0f / fmaxf(dgf, 1.0f);
        float sw = 1.0f - dgf / (dgf + 1e-8f);
        float2 ev = ((const float2*)(iemb + node * 64))[l];
        float v0 = sw * ev.x + s0 * inv;
        float v1 = sw * ev.y + s1 * inv;
        ri1[node * 32 + l] = (unsigned)f2bf(v0) | ((unsigned)f2bf(v1) << 16);
    }
}

// ---- batch rating means: ru1c[b]=mean(iemb[li]), ru2c[b]=mean(ri1[li]) ----
__global__ void k_batch_rat(const int* __restrict__ users, const float* __restrict__ iemb,
                            const u16* __restrict__ ri1, const int* __restrict__ csr,
                            const int* __restrict__ ustart, const int* __restrict__ udeg,
                            u16* __restrict__ ru1c, u16* __restrict__ ru2c) {
    int b = blockIdx.x * 4 + (threadIdx.x >> 6);
    int lane = threadIdx.x & 63;
    if (b >= NBATCH) return;
    int u = users[b];
    int j = ustart[u], dg = udeg[u], end = j + dg;
    float a1 = 0.f, a2 = 0.f, b1 = 0.f, b2 = 0.f;
    for (; j + 1 < end; j += 2) {
        int i0 = csr[j], i1 = csr[j + 1];
        a1 += iemb[i0 * 64 + lane];
        b1 += iemb[i1 * 64 + lane];
        a2 += bf2f(ri1[i0 * 64 + lane]);
        b2 += bf2f(ri1[i1 * 64 + lane]);
    }
    if (j < end) {
        int i0 = csr[j];
        a1 += iemb[i0 * 64 + lane];
        a2 += bf2f(ri1[i0 * 64 + lane]);
    }
    float inv = 1.0f / fmaxf((float)dg, 1.0f);
    ru1c[b * 64 + lane] = f2bf((a1 + b1) * inv);
    ru2c[b * 64 + lane] = f2bf((a2 + b2) * inv);
}

// ---- soc1 = mean(uembh[social sources]); only where needed; pair-packed ----
__global__ void k_gather_soc(const unsigned* __restrict__ uh32,
                             const int* __restrict__ csr, const int* __restrict__ sstart,
                             const int* __restrict__ sdeg,
                             const unsigned char* __restrict__ needed,
                             unsigned* __restrict__ soc1) {
    int node = blockIdx.x * 4 + (threadIdx.x >> 6);
    int lane = threadIdx.x & 63;
    if (node >= NUSERS) return;
    if (!needed[node]) return;   // row never read -> skip
    int half = lane >> 5, l = lane & 31;
    int j = sstart[node], dg = sdeg[node], end = j + dg;
    float a0 = 0.f, b0 = 0.f, a1 = 0.f, b1 = 0.f, a2 = 0.f, b2 = 0.f, a3 = 0.f, b3 = 0.f;
    for (; j + 7 < end; j += 8) {                 // 4 insts = 8 rows in flight
        unsigned w0 = uh32[csr[j     + half] * 32 + l];
        unsigned w1 = uh32[csr[j + 2 + half] * 32 + l];
        unsigned w2 = uh32[csr[j + 4 + half] * 32 + l];
        unsigned w3 = uh32[csr[j + 6 + half] * 32 + l];
        acc2(w0, a0, b0); acc2(w1, a1, b1); acc2(w2, a2, b2); acc2(w3, a3, b3);
    }
    for (; j < end; j += 2) {                     // predicated tail
        int idx = j + half;
        if (idx < end) { unsigned w = uh32[csr[idx] * 32 + l]; acc2(w, a0, b0); }
    }
    float s0 = (a0 + a1) + (a2 + a3);
    float s1 = (b0 + b1) + (b2 + b3);
    s0 += __shfl_xor(s0, 32);
    s1 += __shfl_xor(s1, 32);
    if (half == 0) {
        float inv = 1.0f / fmaxf((float)dg, 1.0f);
        soc1[node * 32 + l] = (unsigned)f2bf(s0 * inv) | ((unsigned)f2bf(s1 * inv) << 16);
    }
}

// ---- fused batch social mean + epilogue; one wave per batch element ----
__global__ void k_final(const int* __restrict__ users, const int* __restrict__ items,
                        const float* __restrict__ uemb, const float* __restrict__ iemb,
                        const u16* __restrict__ soc1, const int* __restrict__ csr,
                        const int* __restrict__ sstart, const int* __restrict__ sdeg,
                        const u16* __restrict__ ru1c, const u16* __restrict__ ru2c,
                        const int* __restrict__ udeg, float* __restrict__ out) {
    int b = blockIdx.x * 4 + (threadIdx.x >> 6);
    int d = threadIdx.x & 63;
    if (b >= NBATCH) return;
    int u = users[b], it = items[b];
    int j = sstart[u], dg = sdeg[u], end = j + dg;
    float a = 0.f, a2_ = 0.f;
    for (; j + 1 < end; j += 2) {
        int c0 = csr[j], c1 = csr[j + 1];
        a   += bf2f(soc1[c0 * 64 + d]);
        a2_ += bf2f(soc1[c1 * 64 + d]);
    }
    if (j < end) a += bf2f(soc1[csr[j] * 64 + d]);
    float s2 = (a + a2_) / fmaxf((float)dg, 1.0f);
    float ud = (float)udeg[u];
    float usw = 1.0f - ud / (ud + 1e-8f);       // f32: 1 if deg==0 else 0
    float ue = uemb[u * 64 + d];
    float s1 = bf2f(soc1[u * 64 + d]);
    float r1 = usw * ue + bf2f(ru1c[b * 64 + d]);
    float r2 = usw * r1 + bf2f(ru2c[b * 64 + d]);
    float fu = ue + 0.5f * (s1 + r1) + 0.5f * (s2 + r2);
    float iv = iemb[it * 64 + d];
    out[NBATCH + b * 64 + d]               = fu;
    out[NBATCH + NBATCH * 64 + b * 64 + d] = iv;
    float p = fu * iv;
    #pragma unroll
    for (int o = 32; o > 0; o >>= 1) p += __shfl_down(p, o);
    if (d == 0) out[b] = 1.0f / (1.0f + __expf(-p));
}

extern "C" void kernel_launch(void* const* d_in, const int* in_sizes, int n_in,
                              void* d_out, int out_size, void* d_ws, size_t ws_size,
                              hipStream_t stream) {
    const float* uemb  = (const float*)d_in[0];
    const float* iemb  = (const float*)d_in[1];
    const int*   users = (const int*)d_in[2];
    const int*   items = (const int*)d_in[3];
    const int*   ssrc  = (const int*)d_in[4];
    const int*   sdst  = (const int*)d_in[5];
    const int*   lu    = (const int*)d_in[6];
    const int*   li    = (const int*)d_in[7];
    float* out = (float*)d_out;

    if (ws_size < (size_t)WS_FLOATS * 4) return;  // would show absmax==0.5 diagnostic

    int*           W      = (int*)d_ws;
    int*           gcnt   = W + OFF_GC;
    int*           gbase  = W + OFF_GB;
    int*           gcur   = W + OFF_GCUR;
    unsigned*      bits   = (unsigned*)(W + OFF_BITS);
    unsigned char* needed = (unsigned char*)(W + OFF_NEED);
    int*           ideg   = W + OFF_IDEG;
    int*           udeg   = W + OFF_UDEG;
    int*           sdeg   = W + OFF_SDEG;
    int*           istart = W + OFF_ISTART;
    int*           ustart = W + OFF_USTART;
    int*           sstart = W + OFF_SSTART;
    int*           partLI = W + OFF_PARTLI;
    int*           partLU = W + OFF_PARTLU;
    int*           partSD = W + OFF_PARTSD;
    u16*           uembh  = (u16*)(W + OFF_UEMBH);   // overlays part* (post-passD)
    int*           csrli  = W + OFF_CSRLI;
    int*           csrlu  = W + OFF_CSRLU;
    int*           csrsd  = W + OFF_CSRSD;
    u16*           ri1    = (u16*)(W + OFF_RI1);
    u16*           soc1   = (u16*)(W + OFF_SOC1);    // overlays csrli/csrlu/ri1
    u16*           ru1c   = (u16*)(W + OFF_RU1C);
    u16*           ru2c   = (u16*)(W + OFF_RU2C);

    hipMemsetAsync(d_ws, 0, (size_t)OFF_ZEND * 4, stream);   // gcnt + bits + needed

    const int B = 256;

    // CSR build (bucket-partitioned, chunked writes, LDS-bitmask membership)
    k_slot<<<(NBATCH + B - 1) / B, B, 0, stream>>>(users, bits, needed);
    k_passA<<<NBLK_E, B, 0, stream>>>(lu, li, sdst, ssrc, bits, gcnt, needed);
    k_passB<<<1, B, 0, stream>>>(gcnt, gbase, gcur);
    k_passC<<<NBLK_E, B, 0, stream>>>(lu, li, sdst, ssrc, bits, gcur,
                                      partLI, partLU, partSD);
    k_passD<<<588, B, 0, stream>>>(gcnt, gbase, partLI, partLU, partSD,
                                   csrli, csrlu, csrsd, ideg, udeg, sdeg,
                                   istart, ustart, sstart);

    // bf16 shadow of uemb (part* now dead)
    k_cvt<<<(NUSERS * 16 + B - 1) / B, B, 0, stream>>>(uemb, uembh);

    // rating branch
    k_gather_item<<<(NITEMS + 3) / 4, B, 0, stream>>>(iemb, (const unsigned*)uembh,
                                                      csrli, istart, ideg, (unsigned*)ri1);
    k_batch_rat<<<(NBATCH + 3) / 4, B, 0, stream>>>(users, iemb, ri1, csrlu, ustart,
                                                    udeg, ru1c, ru2c);
    // social branch (soc1 overlay only covers dead csrli/csrlu/ri1)
    k_gather_soc<<<(NUSERS + 3) / 4, B, 0, stream>>>((const unsigned*)uembh, csrsd,
                                                     sstart, sdeg, needed, (unsigned*)soc1);

    // fused batch social mean + epilogue
    k_final<<<(NBATCH + 3) / 4, B, 0, stream>>>(users, items, uemb, iemb, soc1,
                                                csrsd, sstart, sdeg, ru1c, ru2c, udeg, out);
}